// Round 14
// baseline (922.505 us; speedup 1.0000x reference)
//
#include <hip/hip_runtime.h>

static constexpr int GRAPHS = 256;
static constexpr int SCAN_CHUNK = 1024;
static constexpr int XCDS = 8;
static constexpr int SREP = 8;  // stats replicas (atomic de-contention)

typedef _Float16 h16;
typedef _Float16 h16x2 __attribute__((ext_vector_type(2)));
typedef _Float16 h16x4 __attribute__((ext_vector_type(4)));
typedef _Float16 v8h __attribute__((ext_vector_type(8)));
typedef float v4f __attribute__((ext_vector_type(4)));

__device__ __forceinline__ float lrelu(float v) { return fmaxf(v, 0.2f * v); }
__device__ __forceinline__ int rfl(int v) { return __builtin_amdgcn_readfirstlane(v); }

// Inline BN coef from replicated stats slabs: A=g/sqrt(var+eps), B=b-mu*A.
// Caller: threads tid<D fill csh[tid]=A, csh[D+tid]=B. All threads must reach the
// following __syncthreads().
template <int D>
__device__ __forceinline__ void coef_from_stats(const double* __restrict__ stats,
                                                const float* __restrict__ g,
                                                const float* __restrict__ b, float* csh, int tid,
                                                int n) {
  if (tid < D) {
    double s1 = 0.0, s2 = 0.0;
#pragma unroll
    for (int r = 0; r < SREP; ++r) {
      s1 += stats[r * 256 + tid];
      s2 += stats[r * 256 + D + tid];
    }
    double inv_n = 1.0 / (double)n;
    double mu = s1 * inv_n;
    double var = s2 * inv_n - mu * mu;
    float A = (float)(1.0 / sqrt(var + 1e-5)) * g[tid];
    csh[tid] = A;
    csh[D + tid] = b[tid] - (float)mu * A;
  }
}

// ---------------- utility ----------------
__global__ void zero_f32_kernel(float* __restrict__ p, int n) {
  int i = blockIdx.x * blockDim.x + threadIdx.x;
  if (i < n) p[i] = 0.0f;
}

// ---------------- CSR build ----------------
__global__ void init_counts_kernel(int* __restrict__ cnt, int n) {
  int i = blockIdx.x * blockDim.x + threadIdx.x;
  if (i < n) cnt[i] = 1;  // self loop
}

// XCD-bucketed count: bucket p's counter window stays in one XCD's L2.
__global__ void count_edges_kernel(const int* __restrict__ ei, int* __restrict__ cnt, int E,
                                   int nb) {
  int p = blockIdx.x & (XCDS - 1);
  int lo = p * nb, hi = lo + nb;
  int nchunks = gridDim.x >> 3;
  int chunk = blockIdx.x >> 3;
  int stride = nchunks * blockDim.x;
  for (int e = chunk * blockDim.x + threadIdx.x; e < E; e += stride) {
    int c = ei[E + e];
    if (c >= lo && c < hi) atomicAdd(&cnt[c], 1);
  }
}

__global__ void block_sum_kernel(const int* __restrict__ counts, int* __restrict__ partial,
                                 int n) {
  __shared__ int sh[256];
  int base = blockIdx.x * SCAN_CHUNK;
  int t = threadIdx.x;
  int lim = min(base + SCAN_CHUNK, n);
  int s = 0;
  for (int i = base + t; i < lim; i += 256) s += counts[i];
  sh[t] = s;
  __syncthreads();
  for (int off = 128; off > 0; off >>= 1) {
    if (t < off) sh[t] += sh[t + off];
    __syncthreads();
  }
  if (t == 0) partial[blockIdx.x] = sh[0];
}

__global__ void partial_scan_kernel(int* __restrict__ partial, int* __restrict__ rowptr,
                                    int nblocks, int n) {
  __shared__ int sh[256];
  int t = threadIdx.x;
  int v = (t < nblocks) ? partial[t] : 0;
  sh[t] = v;
  __syncthreads();
  for (int off = 1; off < 256; off <<= 1) {
    int u = (t >= off) ? sh[t - off] : 0;
    __syncthreads();
    sh[t] += u;
    __syncthreads();
  }
  if (t < nblocks) partial[t] = sh[t] - v;
  if (t == 255) rowptr[n] = sh[255];
}

__global__ void chunk_scan_kernel(const int* __restrict__ counts, const int* __restrict__ partial,
                                  int* __restrict__ rowptr, int n) {
  __shared__ int sh[256];
  int base = blockIdx.x * SCAN_CHUNK;
  int t = threadIdx.x;
  int i0 = base + t * 4;
  int c0 = 0, c1 = 0, c2 = 0, c3 = 0;
  if (i0 + 3 < n) {
    int4 c = *(const int4*)(counts + i0);
    c0 = c.x;
    c1 = c.y;
    c2 = c.z;
    c3 = c.w;
  } else {
    if (i0 < n) c0 = counts[i0];
    if (i0 + 1 < n) c1 = counts[i0 + 1];
    if (i0 + 2 < n) c2 = counts[i0 + 2];
  }
  int tot = c0 + c1 + c2 + c3;
  sh[t] = tot;
  __syncthreads();
  for (int off = 1; off < 256; off <<= 1) {
    int u = (t >= off) ? sh[t - off] : 0;
    __syncthreads();
    sh[t] += u;
    __syncthreads();
  }
  int run = partial[blockIdx.x] + sh[t] - tot;
  if (i0 < n) { rowptr[i0] = run; run += c0; }
  if (i0 + 1 < n) { rowptr[i0 + 1] = run; run += c1; }
  if (i0 + 2 < n) { rowptr[i0 + 2] = run; run += c2; }
  if (i0 + 3 < n) { rowptr[i0 + 3] = run; }
}

__global__ void finalize_csr_kernel(const int* __restrict__ rowptr, float* __restrict__ dis,
                                    int* __restrict__ cursor, int* __restrict__ csr, int n) {
  int i = blockIdx.x * blockDim.x + threadIdx.x;
  if (i >= n) return;
  int s = rowptr[i], e = rowptr[i + 1];
  dis[i] = rsqrtf((float)(e - s));
  csr[s] = i;
  cursor[i] = s + 1;
}

__global__ void fill_edges_kernel(const int* __restrict__ ei, int* __restrict__ cursor,
                                  int* __restrict__ csr, int E, int nb) {
  int p = blockIdx.x & (XCDS - 1);
  int lo = p * nb, hi = lo + nb;
  int nchunks = gridDim.x >> 3;
  int chunk = blockIdx.x >> 3;
  int stride = nchunks * blockDim.x;
  for (int e = chunk * blockDim.x + threadIdx.x; e < E; e += stride) {
    int c = ei[E + e];
    if (c >= lo && c < hi) {
      int pos = atomicAdd(&cursor[c], 1);
      csr[pos] = ei[e];
    }
  }
}

// ---------------- fused weight transposes ----------------
__global__ void wt_all_kernel(const float* __restrict__ w0, const float* __restrict__ w1,
                              const float* __restrict__ w2, const float* __restrict__ w3,
                              const float* __restrict__ w4, h16* __restrict__ t0,
                              h16* __restrict__ t1, h16* __restrict__ t2, h16* __restrict__ t3,
                              h16* __restrict__ t4) {
  int gid = blockIdx.x * blockDim.x + threadIdx.x;
  if (gid < 4096) {
    int k = gid / 64, n = gid % 64;
    t0[n * 64 + k] = (h16)w0[gid];
  } else if (gid < 12288) {
    int i = gid - 4096;
    int k = i / 128, n = i % 128;
    t1[n * 64 + k] = (h16)w1[i];
  } else if (gid < 28672) {
    int i = gid - 12288;
    int k = i / 128, n = i % 128;
    t2[n * 128 + k] = (h16)w2[i];
  } else if (gid < 45056) {
    int i = gid - 28672;
    int k = i / 128, n = i % 128;
    t3[n * 128 + k] = (h16)w3[i];
  } else if (gid < 53248) {
    int i = gid - 45056;
    int k = i / 64, n = i % 64;
    t4[n * 128 + k] = (h16)w4[i];
  }
}

// ---------------- MFMA GEMM ----------------
// COEFIN: BN-apply computed inline from stats+g+b applied to input x.
// ATT: fused attention coefficients (asrc/adst) from fp32 acc rows; C = N/4.
template <int K, int N, bool STATS, bool COEFIN, bool ATT>
__global__ void gemm_mfma_kernel(const h16* __restrict__ x, const h16* __restrict__ WT,
                                 const float* __restrict__ bias,
                                 const double* __restrict__ statsIn, const float* __restrict__ gIn,
                                 const float* __restrict__ bIn, h16* __restrict__ out,
                                 double* __restrict__ statsOut, const float* __restrict__ a_src,
                                 const float* __restrict__ a_dst, float* __restrict__ asrcO,
                                 float* __restrict__ adstO, int n_nodes) {
  constexpr int KP = K + 8;
  constexpr int NT = N / 16;
  constexpr int C = N / 4;  // head width for ATT
  __shared__ h16 Ah[128 * KP];
  __shared__ h16 Bs[N * KP];
  __shared__ float sh1[N], sh2[N];
  __shared__ float csh[COEFIN ? 2 * K : 1];
  int tid = threadIdx.x;
  int node0 = blockIdx.x * 128;
  int limit = min(128, n_nodes - node0);
  if (STATS && tid < N) {
    sh1[tid] = 0.f;
    sh2[tid] = 0.f;
  }
  if (COEFIN) {
    coef_from_stats<K>(statsIn, gIn, bIn, csh, tid, n_nodes);
    __syncthreads();
  }
  for (int i = tid; i < 128 * (K / 8); i += 256) {
    int row = i / (K / 8), kb = i % (K / 8);
    v8h v = {};
    if (row < limit) {
      v = *(const v8h*)(x + (size_t)(node0 + row) * K + kb * 8);
      if (COEFIN) {
#pragma unroll
        for (int j = 0; j < 8; ++j)
          v[j] = (h16)fmaf((float)v[j], csh[kb * 8 + j], csh[K + kb * 8 + j]);
      }
    }
    *(v8h*)(Ah + row * KP + kb * 8) = v;
  }
  for (int i = tid; i < N * (K / 8); i += 256) {
    int nrow = i / (K / 8), kb = i % (K / 8);
    *(v8h*)(Bs + nrow * KP + kb * 8) = *(const v8h*)(WT + (size_t)nrow * K + kb * 8);
  }
  __syncthreads();

  int w = tid >> 6, lane = tid & 63, quad = lane >> 4, l16 = lane & 15;
  v4f acc[2][NT];
#pragma unroll
  for (int rt = 0; rt < 2; ++rt)
#pragma unroll
    for (int nt = 0; nt < NT; ++nt) acc[rt][nt] = (v4f){0.f, 0.f, 0.f, 0.f};

  int rowb = w * 32;
#pragma unroll
  for (int ks = 0; ks < K / 32; ++ks) {
    v8h a0 = *(const v8h*)(Ah + (rowb + l16) * KP + ks * 32 + quad * 8);
    v8h a1 = *(const v8h*)(Ah + (rowb + 16 + l16) * KP + ks * 32 + quad * 8);
#pragma unroll
    for (int nt = 0; nt < NT; ++nt) {
      v8h b = *(const v8h*)(Bs + (nt * 16 + l16) * KP + ks * 32 + quad * 8);
      acc[0][nt] = __builtin_amdgcn_mfma_f32_16x16x32_f16(a0, b, acc[0][nt], 0, 0, 0);
      acc[1][nt] = __builtin_amdgcn_mfma_f32_16x16x32_f16(a1, b, acc[1][nt], 0, 0, 0);
    }
  }

#pragma unroll
  for (int nt = 0; nt < NT; ++nt) {
    int col = nt * 16 + l16;
    float bv = bias ? bias[col] : 0.f;
    float p1 = 0.f, p2 = 0.f;
#pragma unroll
    for (int rt = 0; rt < 2; ++rt) {
#pragma unroll
      for (int reg = 0; reg < 4; ++reg) {
        int row = rowb + rt * 16 + quad * 4 + reg;
        if (row < limit) {
          float v = acc[rt][nt][reg] + bv;
          out[(size_t)(node0 + row) * N + col] = (h16)v;
          if (STATS) {
            p1 += v;
            p2 = fmaf(v, v, p2);
          }
        }
      }
    }
    if (STATS) {
      atomicAdd(&sh1[col], p1);
      atomicAdd(&sh2[col], p2);
    }
  }

  if (ATT) {
    // per-lane attention weights for each nt column group
    float wS[NT], wD[NT];
#pragma unroll
    for (int nt = 0; nt < NT; ++nt) {
      int h = (C == 16) ? nt : (nt >> 1);
      int cp = (C == 16) ? l16 : ((nt & 1) * 16 + l16);
      wS[nt] = a_src[h * C + cp];
      wD[nt] = a_dst[h * C + cp];
    }
#pragma unroll
    for (int rt = 0; rt < 2; ++rt) {
#pragma unroll
      for (int reg = 0; reg < 4; ++reg) {
        int row = rowb + rt * 16 + quad * 4 + reg;
        float s0 = 0.f, s1a = 0.f, s2a = 0.f, s3 = 0.f;
        float d0 = 0.f, d1 = 0.f, d2 = 0.f, d3 = 0.f;
#pragma unroll
        for (int nt = 0; nt < NT; ++nt) {
          int h = (C == 16) ? nt : (nt >> 1);
          float v = acc[rt][nt][reg];
          if (h == 0) {
            s0 = fmaf(v, wS[nt], s0);
            d0 = fmaf(v, wD[nt], d0);
          } else if (h == 1) {
            s1a = fmaf(v, wS[nt], s1a);
            d1 = fmaf(v, wD[nt], d1);
          } else if (h == 2) {
            s2a = fmaf(v, wS[nt], s2a);
            d2 = fmaf(v, wD[nt], d2);
          } else {
            s3 = fmaf(v, wS[nt], s3);
            d3 = fmaf(v, wD[nt], d3);
          }
        }
#pragma unroll
        for (int m = 1; m < 16; m <<= 1) {
          s0 += __shfl_xor(s0, m, 64);
          s1a += __shfl_xor(s1a, m, 64);
          s2a += __shfl_xor(s2a, m, 64);
          s3 += __shfl_xor(s3, m, 64);
          d0 += __shfl_xor(d0, m, 64);
          d1 += __shfl_xor(d1, m, 64);
          d2 += __shfl_xor(d2, m, 64);
          d3 += __shfl_xor(d3, m, 64);
        }
        if (row < limit && l16 < 4) {
          float sv = (l16 == 0) ? s0 : (l16 == 1) ? s1a : (l16 == 2) ? s2a : s3;
          float dv = (l16 == 0) ? d0 : (l16 == 1) ? d1 : (l16 == 2) ? d2 : d3;
          asrcO[(node0 + row) * 4 + l16] = sv;
          adstO[(node0 + row) * 4 + l16] = dv;
        }
      }
    }
  }

  if (STATS) {
    __syncthreads();
    double* st = statsOut + (blockIdx.x & (SREP - 1)) * 256;
    if (tid < N) {
      atomicAdd(&st[tid], (double)sh1[tid]);
      atomicAdd(&st[N + tid], (double)sh2[tid]);
    }
  }
}

// ---------------- VALU GEMM (K=16 only) ----------------
template <int K, int DOUT, int MT, bool STATS>
__global__ void gemm_tile_kernel(const h16* __restrict__ x, const float* __restrict__ W,
                                 const float* __restrict__ bias, h16* __restrict__ out,
                                 double* __restrict__ stats, int n_nodes) {
  constexpr int COLG = DOUT / 4;
  constexpr int ROWG = 256 / COLG;
  constexpr int NODES = ROWG * MT;
  constexpr int KP = K + 4;
  __shared__ float xs[NODES * KP];
  __shared__ float sh1[DOUT], sh2[DOUT];
  int tid = threadIdx.x;
  if (STATS && tid < DOUT) {
    sh1[tid] = 0.f;
    sh2[tid] = 0.f;
  }
  int node0 = blockIdx.x * NODES;
  int limit = min(NODES, n_nodes - node0);
  const h16x4* src = (const h16x4*)(x + (size_t)node0 * K);
  int tile_q = (limit * K) >> 2;
  for (int i = tid; i < tile_q; i += 256) {
    h16x4 v = src[i];
    int row = i / (K / 4), cq = i % (K / 4);
    float4 f;
    f.x = (float)v[0];
    f.y = (float)v[1];
    f.z = (float)v[2];
    f.w = (float)v[3];
    *(float4*)(xs + row * KP + cq * 4) = f;
  }
  __syncthreads();
  int cg = tid % COLG, rg = tid / COLG;
  int c0 = cg * 4;
  float acc[MT][4];
#pragma unroll
  for (int m = 0; m < MT; ++m)
#pragma unroll
    for (int i = 0; i < 4; ++i) acc[m][i] = 0.f;

  for (int k4 = 0; k4 < K / 4; ++k4) {
    int k = k4 * 4;
    float4 w0 = *(const float4*)(W + (size_t)(k + 0) * DOUT + c0);
    float4 w1 = *(const float4*)(W + (size_t)(k + 1) * DOUT + c0);
    float4 w2 = *(const float4*)(W + (size_t)(k + 2) * DOUT + c0);
    float4 w3 = *(const float4*)(W + (size_t)(k + 3) * DOUT + c0);
#pragma unroll
    for (int m = 0; m < MT; ++m) {
      float4 xv = *(const float4*)(xs + (rg * MT + m) * KP + k);
      acc[m][0] = fmaf(xv.x, w0.x, acc[m][0]);
      acc[m][1] = fmaf(xv.x, w0.y, acc[m][1]);
      acc[m][2] = fmaf(xv.x, w0.z, acc[m][2]);
      acc[m][3] = fmaf(xv.x, w0.w, acc[m][3]);
      acc[m][0] = fmaf(xv.y, w1.x, acc[m][0]);
      acc[m][1] = fmaf(xv.y, w1.y, acc[m][1]);
      acc[m][2] = fmaf(xv.y, w1.z, acc[m][2]);
      acc[m][3] = fmaf(xv.y, w1.w, acc[m][3]);
      acc[m][0] = fmaf(xv.z, w2.x, acc[m][0]);
      acc[m][1] = fmaf(xv.z, w2.y, acc[m][1]);
      acc[m][2] = fmaf(xv.z, w2.z, acc[m][2]);
      acc[m][3] = fmaf(xv.z, w2.w, acc[m][3]);
      acc[m][0] = fmaf(xv.w, w3.x, acc[m][0]);
      acc[m][1] = fmaf(xv.w, w3.y, acc[m][1]);
      acc[m][2] = fmaf(xv.w, w3.z, acc[m][2]);
      acc[m][3] = fmaf(xv.w, w3.w, acc[m][3]);
    }
  }
  float4 bv = make_float4(0.f, 0.f, 0.f, 0.f);
  if (bias) bv = *(const float4*)(bias + c0);
  float p1[4] = {0.f, 0.f, 0.f, 0.f}, p2[4] = {0.f, 0.f, 0.f, 0.f};
#pragma unroll
  for (int m = 0; m < MT; ++m) {
    int node = node0 + rg * MT + m;
    if (node < n_nodes) {
      float v0 = acc[m][0] + bv.x, v1 = acc[m][1] + bv.y;
      float v2 = acc[m][2] + bv.z, v3 = acc[m][3] + bv.w;
      h16x4 r;
      r[0] = (h16)v0;
      r[1] = (h16)v1;
      r[2] = (h16)v2;
      r[3] = (h16)v3;
      *(h16x4*)(out + (size_t)node * DOUT + c0) = r;
      if (STATS) {
        p1[0] += v0;
        p1[1] += v1;
        p1[2] += v2;
        p1[3] += v3;
        p2[0] = fmaf(v0, v0, p2[0]);
        p2[1] = fmaf(v1, v1, p2[1]);
        p2[2] = fmaf(v2, v2, p2[2]);
        p2[3] = fmaf(v3, v3, p2[3]);
      }
    }
  }
  if (STATS) {
#pragma unroll
    for (int i = 0; i < 4; ++i) {
      atomicAdd(&sh1[c0 + i], p1[i]);
      atomicAdd(&sh2[c0 + i], p2[i]);
    }
    __syncthreads();
    double* st = stats + (blockIdx.x & (SREP - 1)) * 256;
    if (tid < DOUT) {
      atomicAdd(&st[tid], (double)sh1[tid]);
      atomicAdd(&st[DOUT + tid], (double)sh2[tid]);
    }
  }
}

// ---------------- standalone BN stats (L3 only) ----------------
template <int D>
__global__ void bn_stats_kernel(const h16* __restrict__ x, double* __restrict__ stats, int n) {
  int tid = threadIdx.x;
  int c = tid & (D - 1);
  const int rpb = 256 / D;
  float s1 = 0.f, s2 = 0.f;
  for (int r = blockIdx.x * rpb + tid / D; r < n; r += gridDim.x * rpb) {
    float v = (float)x[(size_t)r * D + c];
    s1 += v;
    s2 = fmaf(v, v, s2);
  }
  double* st = stats + (blockIdx.x & (SREP - 1)) * 256;
  atomicAdd(&st[c], (double)s1);
  atomicAdd(&st[D + c], (double)s2);
}

// ---------------- GCN aggregation ----------------
__global__ void gcn_agg16_kernel(const float* __restrict__ h, const int* __restrict__ rowptr,
                                 const int* __restrict__ csr, const float* __restrict__ dis,
                                 h16* __restrict__ out, int n) {
  int wave = (blockIdx.x * blockDim.x + threadIdx.x) >> 6;
  int lane = threadIdx.x & 63;
  if (wave >= n) return;
  int s = rowptr[wave], e = rowptr[wave + 1];
  int q = lane >> 4, c = lane & 15;
  float acc = 0.f;
  for (int k = s + q; k < e; k += 4) {
    int j = csr[k];
    acc = fmaf(dis[j], h[(size_t)j * 16 + c], acc);
  }
  acc += __shfl_xor(acc, 16, 64);
  acc += __shfl_xor(acc, 32, 64);
  if (lane < 16) out[(size_t)wave * 16 + lane] = (h16)(dis[wave] * acc);
}

__global__ void gcn_agg64_kernel(const h16* __restrict__ h, const int* __restrict__ rowptr,
                                 const int* __restrict__ csr, const float* __restrict__ dis,
                                 const float* __restrict__ bias, h16* __restrict__ out, int n) {
  int wave = (blockIdx.x * blockDim.x + threadIdx.x) >> 6;
  int lane = threadIdx.x & 63;
  if (wave >= n) return;
  int s = rfl(rowptr[wave]);
  int e = rfl(rowptr[wave + 1]);
  float a[4] = {0.f, 0.f, 0.f, 0.f};
  int k = s;
  for (; k + 8 <= e; k += 8) {
    int j[8];
    float d[8];
#pragma unroll
    for (int u = 0; u < 8; ++u) j[u] = rfl(csr[k + u]);
#pragma unroll
    for (int u = 0; u < 8; ++u) d[u] = dis[j[u]];
#pragma unroll
    for (int u = 0; u < 8; ++u) {
      const h16* rp = h + (size_t)j[u] * 64;
      a[u & 3] = fmaf(d[u], (float)rp[lane], a[u & 3]);
    }
  }
  for (; k + 4 <= e; k += 4) {
    int j[4];
#pragma unroll
    for (int u = 0; u < 4; ++u) j[u] = rfl(csr[k + u]);
#pragma unroll
    for (int u = 0; u < 4; ++u) {
      const h16* rp = h + (size_t)j[u] * 64;
      a[u] = fmaf(dis[j[u]], (float)rp[lane], a[u]);
    }
  }
  for (; k < e; ++k) {
    int j0 = rfl(csr[k]);
    const h16* rp = h + (size_t)j0 * 64;
    a[0] = fmaf(dis[j0], (float)rp[lane], a[0]);
  }
  float b0 = bias ? bias[lane] : 0.f;
  out[(size_t)wave * 64 + lane] = (h16)fmaf(dis[wave], (a[0] + a[1]) + (a[2] + a[3]), b0);
}

// D=128 with inline BN-coef (stats+g+b) + lrelu applied to gathered elements.
template <bool COEF>
__global__ void gcn_agg128_kernel(const h16* __restrict__ h, const int* __restrict__ rowptr,
                                  const int* __restrict__ csr, const float* __restrict__ dis,
                                  const double* __restrict__ statsIn, const float* __restrict__ g,
                                  const float* __restrict__ b, h16* __restrict__ out, int n) {
  __shared__ float csh[256];
  int tid = threadIdx.x;
  if (COEF) {
    coef_from_stats<128>(statsIn, g, b, csh, tid, n);
    __syncthreads();
  }
  int wave = (blockIdx.x * blockDim.x + tid) >> 6;
  int lane = tid & 63;
  if (wave >= n) return;
  int s = rfl(rowptr[wave]);
  int e = rfl(rowptr[wave + 1]);
  int c2 = lane * 2;
  float2 A2 = make_float2(0.f, 0.f), B2 = make_float2(0.f, 0.f);
  if (COEF) {
    A2 = make_float2(csh[c2], csh[c2 + 1]);
    B2 = make_float2(csh[128 + c2], csh[128 + c2 + 1]);
  }
  float a0[4] = {0.f, 0.f, 0.f, 0.f};
  float a1[4] = {0.f, 0.f, 0.f, 0.f};
  int k = s;
  for (; k + 8 <= e; k += 8) {
    int j[8];
    float d[8];
#pragma unroll
    for (int u = 0; u < 8; ++u) j[u] = rfl(csr[k + u]);
#pragma unroll
    for (int u = 0; u < 8; ++u) d[u] = dis[j[u]];
#pragma unroll
    for (int u = 0; u < 8; ++u) {
      const h16* rp = h + (size_t)j[u] * 128;
      h16x2 v = *(const h16x2*)(rp + c2);
      float f0 = (float)v[0], f1 = (float)v[1];
      if (COEF) {
        f0 = lrelu(fmaf(f0, A2.x, B2.x));
        f1 = lrelu(fmaf(f1, A2.y, B2.y));
      }
      a0[u & 3] = fmaf(d[u], f0, a0[u & 3]);
      a1[u & 3] = fmaf(d[u], f1, a1[u & 3]);
    }
  }
  for (; k < e; ++k) {
    int j0 = rfl(csr[k]);
    float d0 = dis[j0];
    const h16* rp = h + (size_t)j0 * 128;
    h16x2 v = *(const h16x2*)(rp + c2);
    float f0 = (float)v[0], f1 = (float)v[1];
    if (COEF) {
      f0 = lrelu(fmaf(f0, A2.x, B2.x));
      f1 = lrelu(fmaf(f1, A2.y, B2.y));
    }
    a0[0] = fmaf(d0, f0, a0[0]);
    a1[0] = fmaf(d0, f1, a1[0]);
  }
  float di = dis[wave];
  h16x2 r;
  r[0] = (h16)(di * ((a0[0] + a0[1]) + (a0[2] + a0[3])));
  r[1] = (h16)(di * ((a1[0] + a1[1]) + (a1[2] + a1[3])));
  *(h16x2*)(out + (size_t)wave * 128 + c2) = r;
}

// ---------------- GAT ----------------
// Dedicated softmax-coef pass (r11 lesson: keep the asrc table L2-resident here).
__global__ void edge_coef_kernel(const int* __restrict__ rowptr, const int* __restrict__ csr,
                                 const float* __restrict__ asrc, const float* __restrict__ adst,
                                 float* __restrict__ exbuf, float* __restrict__ dinv, int n) {
  int wave = (blockIdx.x * blockDim.x + threadIdx.x) >> 6;
  int lane = threadIdx.x & 63;
  if (wave >= n) return;
  int h = lane & 3, es = lane >> 2;
  float ad = adst[wave * 4 + h];
  int s = rowptr[wave], e = rowptr[wave + 1];
  float den = 0.f;
  for (int k = s + es; k < e; k += 16) {
    int j = csr[k];
    float v = __expf(lrelu(asrc[j * 4 + h] + ad));
    exbuf[(size_t)k * 4 + h] = v;
    den += v;
  }
  den += __shfl_xor(den, 4, 64);
  den += __shfl_xor(den, 8, 64);
  den += __shfl_xor(den, 16, 64);
  den += __shfl_xor(den, 32, 64);
  if (lane < 4) dinv[wave * 4 + h] = 1.0f / den;
}

// D=64,C=16: residual BN-apply from inline coef (stats+g+b).
__global__ void gat_agg64_kernel(const h16* __restrict__ h2, const int* __restrict__ rowptr,
                                 const int* __restrict__ csr, const float* __restrict__ exbuf,
                                 const float* __restrict__ dinv, const float* __restrict__ bias,
                                 const h16* __restrict__ xres, const double* __restrict__ statsIn,
                                 const float* __restrict__ g, const float* __restrict__ b,
                                 h16* __restrict__ out, int n) {
  __shared__ float csh[128];
  int tid = threadIdx.x;
  coef_from_stats<64>(statsIn, g, b, csh, tid, n);
  __syncthreads();
  int wave = (blockIdx.x * blockDim.x + tid) >> 6;
  int lane = tid & 63;
  if (wave >= n) return;
  int head = lane >> 4;
  int s = rfl(rowptr[wave]);
  int e = rfl(rowptr[wave + 1]);
  float a[4] = {0.f, 0.f, 0.f, 0.f};
  int k = s;
  for (; k + 8 <= e; k += 8) {
    int j[8];
    float ex[8];
#pragma unroll
    for (int u = 0; u < 8; ++u) {
      j[u] = rfl(csr[k + u]);
      ex[u] = exbuf[(size_t)(k + u) * 4 + head];
    }
#pragma unroll
    for (int u = 0; u < 8; ++u) {
      const h16* rp = h2 + (size_t)j[u] * 64;
      a[u & 3] = fmaf(ex[u], (float)rp[lane], a[u & 3]);
    }
  }
  for (; k + 4 <= e; k += 4) {
    int j[4];
    float ex[4];
#pragma unroll
    for (int u = 0; u < 4; ++u) {
      j[u] = rfl(csr[k + u]);
      ex[u] = exbuf[(size_t)(k + u) * 4 + head];
    }
#pragma unroll
    for (int u = 0; u < 4; ++u) {
      const h16* rp = h2 + (size_t)j[u] * 64;
      a[u] = fmaf(ex[u], (float)rp[lane], a[u]);
    }
  }
  for (; k < e; ++k) {
    int j0 = rfl(csr[k]);
    const h16* rp = h2 + (size_t)j0 * 64;
    a[0] = fmaf(exbuf[(size_t)k * 4 + head], (float)rp[lane], a[0]);
  }
  float dv = dinv[wave * 4 + head];
  size_t base = (size_t)wave * 64;
  float xv = fmaf((float)xres[base + lane], csh[lane], csh[64 + lane]);
  float v0 = ((a[0] + a[1]) + (a[2] + a[3])) * dv + bias[lane] + xv;
  out[base + lane] = (h16)lrelu(v0);
}

// D=128,C=32: residual BN-apply from inline coef.
__global__ void gat_agg128_kernel(const h16* __restrict__ h2, const int* __restrict__ rowptr,
                                  const int* __restrict__ csr, const float* __restrict__ exbuf,
                                  const float* __restrict__ dinv, const float* __restrict__ bias,
                                  const h16* __restrict__ xres, const double* __restrict__ statsIn,
                                  const float* __restrict__ g, const float* __restrict__ b,
                                  h16* __restrict__ out, int n) {
  __shared__ float csh[256];
  int tid = threadIdx.x;
  coef_from_stats<128>(statsIn, g, b, csh, tid, n);
  __syncthreads();
  int wave = (blockIdx.x * blockDim.x + tid) >> 6;
  int lane = tid & 63;
  if (wave >= n) return;
  int head = lane >> 4;
  int c2 = lane * 2;
  int s = rfl(rowptr[wave]);
  int e = rfl(rowptr[wave + 1]);
  float a0[4] = {0.f, 0.f, 0.f, 0.f};
  float a1[4] = {0.f, 0.f, 0.f, 0.f};
  int k = s;
  for (; k + 8 <= e; k += 8) {
    int j[8];
    float ex[8];
#pragma unroll
    for (int u = 0; u < 8; ++u) {
      j[u] = rfl(csr[k + u]);
      ex[u] = exbuf[(size_t)(k + u) * 4 + head];
    }
#pragma unroll
    for (int u = 0; u < 8; ++u) {
      const h16* rp = h2 + (size_t)j[u] * 128;
      h16x2 v = *(const h16x2*)(rp + c2);
      a0[u & 3] = fmaf(ex[u], (float)v[0], a0[u & 3]);
      a1[u & 3] = fmaf(ex[u], (float)v[1], a1[u & 3]);
    }
  }
  for (; k + 4 <= e; k += 4) {
    int j[4];
    float ex[4];
#pragma unroll
    for (int u = 0; u < 4; ++u) {
      j[u] = rfl(csr[k + u]);
      ex[u] = exbuf[(size_t)(k + u) * 4 + head];
    }
#pragma unroll
    for (int u = 0; u < 4; ++u) {
      const h16* rp = h2 + (size_t)j[u] * 128;
      h16x2 v = *(const h16x2*)(rp + c2);
      a0[u] = fmaf(ex[u], (float)v[0], a0[u]);
      a1[u] = fmaf(ex[u], (float)v[1], a1[u]);
    }
  }
  for (; k < e; ++k) {
    int j0 = rfl(csr[k]);
    float e0 = exbuf[(size_t)k * 4 + head];
    const h16* rp = h2 + (size_t)j0 * 128;
    h16x2 v = *(const h16x2*)(rp + c2);
    a0[0] = fmaf(e0, (float)v[0], a0[0]);
    a1[0] = fmaf(e0, (float)v[1], a1[0]);
  }
  float dv = dinv[wave * 4 + head];
  float2 b2 = *(const float2*)(bias + c2);
  size_t base = (size_t)wave * 128;
  h16x2 xr = *(const h16x2*)(xres + base + c2);
  float xr0 = fmaf((float)xr[0], csh[c2], csh[128 + c2]);
  float xr1 = fmaf((float)xr[1], csh[c2 + 1], csh[129 + c2]);
  float v0 = ((a0[0] + a0[1]) + (a0[2] + a0[3])) * dv + b2.x + xr0;
  float v1 = ((a1[0] + a1[1]) + (a1[2] + a1[3])) * dv + b2.y + xr1;
  h16x2 r;
  r[0] = (h16)lrelu(v0);
  r[1] = (h16)lrelu(v1);
  *(h16x2*)(out + base + c2) = r;
}

// ---------------- global mean pool (inline bounds + inline L3 BN coef) ----------------
__global__ void pool_kernel(const h16* __restrict__ x, const int* __restrict__ batch,
                            const double* __restrict__ statsIn, const float* __restrict__ g,
                            const float* __restrict__ b, float* __restrict__ out, int n) {
  __shared__ float sh[4][64];
  __shared__ float csh[128];
  __shared__ int sb[2];
  int tid = threadIdx.x;
  int gid = blockIdx.x;
  coef_from_stats<64>(statsIn, g, b, csh, tid, n);
  if (tid < 2) {  // lower_bound(batch, gid + tid)
    int key = gid + tid;
    int lo = 0, hi = n;
    while (lo < hi) {
      int mid = (lo + hi) >> 1;
      if (batch[mid] < key)
        lo = mid + 1;
      else
        hi = mid;
    }
    sb[tid] = lo;
  }
  __syncthreads();
  int s = sb[0], e = sb[1];
  int lane = tid & 63, w = tid >> 6;
  float acc = 0.f;
  for (int r = s + w; r < e; r += 4) acc += (float)x[(size_t)r * 64 + lane];
  sh[w][lane] = acc;
  __syncthreads();
  if (w == 0) {
    float t = sh[0][lane] + sh[1][lane] + sh[2][lane] + sh[3][lane];
    float cntf = (float)(e - s);
    out[(gid << 6) + lane] = fmaf(csh[lane], t, csh[64 + lane] * cntf) / fmaxf(cntf, 1.0f);
  }
}

// ---------------- host ----------------
extern "C" void kernel_launch(void* const* d_in, const int* in_sizes, int n_in, void* d_out,
                              int out_size, void* d_ws, size_t ws_size, hipStream_t stream) {
  const float* x_in = (const float*)d_in[0];
  const int* ei = (const int*)d_in[1];
  const int* batch = (const int*)d_in[2];
  const float* gcn_w[4] = {(const float*)d_in[3], (const float*)d_in[7], (const float*)d_in[11],
                           (const float*)d_in[15]};
  const float* gcn_b[4] = {(const float*)d_in[4], (const float*)d_in[8], (const float*)d_in[12],
                           (const float*)d_in[16]};
  const float* bn_g[4] = {(const float*)d_in[5], (const float*)d_in[9], (const float*)d_in[13],
                          (const float*)d_in[17]};
  const float* bn_b[4] = {(const float*)d_in[6], (const float*)d_in[10], (const float*)d_in[14],
                          (const float*)d_in[18]};
  const float* gat_w0 = (const float*)d_in[19];
  const float* gat_as0 = (const float*)d_in[20];
  const float* gat_ad0 = (const float*)d_in[21];
  const float* gat_b0 = (const float*)d_in[22];
  const float* gat_w2 = (const float*)d_in[23];
  const float* gat_as2 = (const float*)d_in[24];
  const float* gat_ad2 = (const float*)d_in[25];
  const float* gat_b2 = (const float*)d_in[26];

  const int N = in_sizes[2];      // 100000
  const int E = in_sizes[1] / 2;  // 1600000

  char* wp = (char*)d_ws;
  auto alloc = [&](size_t bytes) -> void* {
    void* p = (void*)wp;
    wp += (bytes + 255) & ~(size_t)255;
    return p;
  };
  double* statsAll = (double*)alloc(4 * SREP * 256 * sizeof(double));
  int* rowptr = (int*)alloc((size_t)(N + 1) * 4);
  int* cursor = (int*)alloc((size_t)N * 4);
  int* partial = (int*)alloc(256 * sizeof(int));
  int* csr = (int*)alloc((size_t)(N + E) * 4);
  float* dis = (float*)alloc((size_t)N * 4);
  h16* bufA = (h16*)alloc((size_t)N * 128 * 2);
  h16* bufB = (h16*)alloc((size_t)N * 128 * 2);
  h16* bufC = (h16*)alloc((size_t)N * 128 * 2);
  float* attS = (float*)alloc((size_t)N * 4 * 4);
  float* attD = (float*)alloc((size_t)N * 4 * 4);
  float* exbuf = (float*)alloc((size_t)(N + E) * 4 * 4);
  float* dinv = (float*)alloc((size_t)N * 4 * 4);
  h16* wt0 = (h16*)alloc(64 * 64 * 2);
  h16* wt1 = (h16*)alloc(64 * 128 * 2);
  h16* wt2 = (h16*)alloc(128 * 128 * 2);
  h16* wt3 = (h16*)alloc(128 * 128 * 2);
  h16* wt4 = (h16*)alloc(128 * 64 * 2);
  if ((size_t)(wp - (char*)d_ws) > ws_size) return;

  double* stats0 = statsAll;
  double* stats1 = statsAll + SREP * 256;
  double* stats2 = statsAll + 2 * SREP * 256;
  double* stats3 = statsAll + 3 * SREP * 256;

  const int B = 256;
  auto cd = [](int a, int b) { return (a + b - 1) / b; };
  const int scan_blocks = cd(N, SCAN_CHUNK);
  const int nbkt = cd(N, XCDS);

  // --- zero + transposes + CSR build ---
  zero_f32_kernel<<<cd(4 * SREP * 512, B), B, 0, stream>>>((float*)statsAll, 4 * SREP * 512);
  wt_all_kernel<<<cd(53248, B), B, 0, stream>>>(gat_w0, gcn_w[1], gcn_w[2], gat_w2, gcn_w[3], wt0,
                                                wt1, wt2, wt3, wt4);
  init_counts_kernel<<<cd(N, B), B, 0, stream>>>(cursor, N);
  count_edges_kernel<<<XCDS * 512, B, 0, stream>>>(ei, cursor, E, nbkt);
  block_sum_kernel<<<scan_blocks, B, 0, stream>>>(cursor, partial, N);
  partial_scan_kernel<<<1, B, 0, stream>>>(partial, rowptr, scan_blocks, N);
  chunk_scan_kernel<<<scan_blocks, B, 0, stream>>>(cursor, partial, rowptr, N);
  finalize_csr_kernel<<<cd(N, B), B, 0, stream>>>(rowptr, dis, cursor, csr, N);
  fill_edges_kernel<<<XCDS * 512, B, 0, stream>>>(ei, cursor, csr, E, nbkt);

  // ---- Layer 0: GCN 16->64 (agg16 -> VALU gemm w/ stats) ----
  gcn_agg16_kernel<<<cd(N * 64, B), B, 0, stream>>>(x_in, rowptr, csr, dis, bufB, N);
  gemm_tile_kernel<16, 64, 8, true>
      <<<cd(N, 128), B, 0, stream>>>(bufB, gcn_w[0], gcn_b[0], bufC, stats0, N);
  // GAT0: MFMA gemm (inline coef0 on input + fused att) -> edge_coef -> gat (inline coef0 res)
  gemm_mfma_kernel<64, 64, false, true, true><<<cd(N, 128), B, 0, stream>>>(
      bufC, wt0, nullptr, stats0, bn_g[0], bn_b[0], bufB, nullptr, gat_as0, gat_ad0, attS, attD,
      N);
  edge_coef_kernel<<<cd(N * 64, B), B, 0, stream>>>(rowptr, csr, attS, attD, exbuf, dinv, N);
  gat_agg64_kernel<<<cd(N * 64, B), B, 0, stream>>>(bufB, rowptr, csr, exbuf, dinv, gat_b0, bufC,
                                                    stats0, bn_g[0], bn_b[0], bufA, N);

  // ---- Layer 1: GCN 64->128 (agg64 -> MFMA gemm w/ stats) ----
  gcn_agg64_kernel<<<cd(N * 64, B), B, 0, stream>>>(bufA, rowptr, csr, dis, nullptr, bufB, N);
  gemm_mfma_kernel<64, 128, true, false, false><<<cd(N, 128), B, 0, stream>>>(
      bufB, wt1, gcn_b[1], nullptr, nullptr, nullptr, bufC, stats1, nullptr, nullptr, nullptr,
      nullptr, N);

  // ---- Layer 2: GCN 128->128 (agg applies inline coef1+lrelu) -> MFMA gemm w/ stats ----
  gcn_agg128_kernel<true>
      <<<cd(N * 64, B), B, 0, stream>>>(bufC, rowptr, csr, dis, stats1, bn_g[1], bn_b[1], bufB, N);
  gemm_mfma_kernel<128, 128, true, false, false><<<cd(N, 128), B, 0, stream>>>(
      bufB, wt2, gcn_b[2], nullptr, nullptr, nullptr, bufA, stats2, nullptr, nullptr, nullptr,
      nullptr, N);
  // GAT2: MFMA gemm (inline coef2 on input + fused att) -> edge_coef -> gat (inline coef2 res)
  gemm_mfma_kernel<128, 128, false, true, true><<<cd(N, 128), B, 0, stream>>>(
      bufA, wt3, nullptr, stats2, bn_g[2], bn_b[2], bufB, nullptr, gat_as2, gat_ad2, attS, attD,
      N);
  edge_coef_kernel<<<cd(N * 64, B), B, 0, stream>>>(rowptr, csr, attS, attD, exbuf, dinv, N);
  gat_agg128_kernel<<<cd(N * 64, B), B, 0, stream>>>(bufB, rowptr, csr, exbuf, dinv, gat_b2, bufA,
                                                     stats2, bn_g[2], bn_b[2], bufC, N);

  // ---- Layer 3: GCN 128->64 (MFMA gemm -> agg64 w/ bias) -> stats ----
  gemm_mfma_kernel<128, 64, false, false, false><<<cd(N, 128), B, 0, stream>>>(
      bufC, wt4, nullptr, nullptr, nullptr, nullptr, bufB, nullptr, nullptr, nullptr, nullptr,
      nullptr, N);
  gcn_agg64_kernel<<<cd(N * 64, B), B, 0, stream>>>(bufB, rowptr, csr, dis, gcn_b[3], bufA, N);
  bn_stats_kernel<64><<<256, 256, 0, stream>>>(bufA, stats3, N);

  // ---- global mean pool (inline bounds + coef3) ----
  pool_kernel<<<GRAPHS, 256, 0, stream>>>(bufA, batch, stats3, bn_g[3], bn_b[3], (float*)d_out, N);
}

// Round 15
// 918.138 us; speedup vs baseline: 1.0048x; 1.0048x over previous
//
#include <hip/hip_runtime.h>

static constexpr int GRAPHS = 256;
static constexpr int SCAN_CHUNK = 1024;
static constexpr int XCDS = 8;
static constexpr int SREP = 8;  // stats replicas (atomic de-contention)

typedef _Float16 h16;
typedef _Float16 h16x2 __attribute__((ext_vector_type(2)));
typedef _Float16 h16x4 __attribute__((ext_vector_type(4)));
typedef _Float16 v8h __attribute__((ext_vector_type(8)));
typedef float v4f __attribute__((ext_vector_type(4)));

__device__ __forceinline__ float lrelu(float v) { return fmaxf(v, 0.2f * v); }
__device__ __forceinline__ int rfl(int v) { return __builtin_amdgcn_readfirstlane(v); }

// ---------------- utility ----------------
__global__ void zero_f32_kernel(float* __restrict__ p, int n) {
  int i = blockIdx.x * blockDim.x + threadIdx.x;
  if (i < n) p[i] = 0.0f;
}

// ---------------- CSR build ----------------
__global__ void init_counts_kernel(int* __restrict__ cnt, int n) {
  int i = blockIdx.x * blockDim.x + threadIdx.x;
  if (i < n) cnt[i] = 1;  // self loop
}

// XCD-bucketed count: bucket p's counter window stays in one XCD's L2.
__global__ void count_edges_kernel(const int* __restrict__ ei, int* __restrict__ cnt, int E,
                                   int nb) {
  int p = blockIdx.x & (XCDS - 1);
  int lo = p * nb, hi = lo + nb;
  int nchunks = gridDim.x >> 3;
  int chunk = blockIdx.x >> 3;
  int stride = nchunks * blockDim.x;
  for (int e = chunk * blockDim.x + threadIdx.x; e < E; e += stride) {
    int c = ei[E + e];
    if (c >= lo && c < hi) atomicAdd(&cnt[c], 1);
  }
}

__global__ void block_sum_kernel(const int* __restrict__ counts, int* __restrict__ partial,
                                 int n) {
  __shared__ int sh[256];
  int base = blockIdx.x * SCAN_CHUNK;
  int t = threadIdx.x;
  int lim = min(base + SCAN_CHUNK, n);
  int s = 0;
  for (int i = base + t; i < lim; i += 256) s += counts[i];
  sh[t] = s;
  __syncthreads();
  for (int off = 128; off > 0; off >>= 1) {
    if (t < off) sh[t] += sh[t + off];
    __syncthreads();
  }
  if (t == 0) partial[blockIdx.x] = sh[0];
}

__global__ void partial_scan_kernel(int* __restrict__ partial, int* __restrict__ rowptr,
                                    int nblocks, int n) {
  __shared__ int sh[256];
  int t = threadIdx.x;
  int v = (t < nblocks) ? partial[t] : 0;
  sh[t] = v;
  __syncthreads();
  for (int off = 1; off < 256; off <<= 1) {
    int u = (t >= off) ? sh[t - off] : 0;
    __syncthreads();
    sh[t] += u;
    __syncthreads();
  }
  if (t < nblocks) partial[t] = sh[t] - v;
  if (t == 255) rowptr[n] = sh[255];
}

__global__ void chunk_scan_kernel(const int* __restrict__ counts, const int* __restrict__ partial,
                                  int* __restrict__ rowptr, int n) {
  __shared__ int sh[256];
  int base = blockIdx.x * SCAN_CHUNK;
  int t = threadIdx.x;
  int i0 = base + t * 4;
  int c0 = 0, c1 = 0, c2 = 0, c3 = 0;
  if (i0 + 3 < n) {
    int4 c = *(const int4*)(counts + i0);
    c0 = c.x;
    c1 = c.y;
    c2 = c.z;
    c3 = c.w;
  } else {
    if (i0 < n) c0 = counts[i0];
    if (i0 + 1 < n) c1 = counts[i0 + 1];
    if (i0 + 2 < n) c2 = counts[i0 + 2];
  }
  int tot = c0 + c1 + c2 + c3;
  sh[t] = tot;
  __syncthreads();
  for (int off = 1; off < 256; off <<= 1) {
    int u = (t >= off) ? sh[t - off] : 0;
    __syncthreads();
    sh[t] += u;
    __syncthreads();
  }
  int run = partial[blockIdx.x] + sh[t] - tot;
  if (i0 < n) { rowptr[i0] = run; run += c0; }
  if (i0 + 1 < n) { rowptr[i0 + 1] = run; run += c1; }
  if (i0 + 2 < n) { rowptr[i0 + 2] = run; run += c2; }
  if (i0 + 3 < n) { rowptr[i0 + 3] = run; }
}

__global__ void finalize_csr_kernel(const int* __restrict__ rowptr, float* __restrict__ dis,
                                    int* __restrict__ cursor, int* __restrict__ csr, int n) {
  int i = blockIdx.x * blockDim.x + threadIdx.x;
  if (i >= n) return;
  int s = rowptr[i], e = rowptr[i + 1];
  dis[i] = rsqrtf((float)(e - s));
  csr[s] = i;
  cursor[i] = s + 1;
}

__global__ void fill_edges_kernel(const int* __restrict__ ei, int* __restrict__ cursor,
                                  int* __restrict__ csr, int E, int nb) {
  int p = blockIdx.x & (XCDS - 1);
  int lo = p * nb, hi = lo + nb;
  int nchunks = gridDim.x >> 3;
  int chunk = blockIdx.x >> 3;
  int stride = nchunks * blockDim.x;
  for (int e = chunk * blockDim.x + threadIdx.x; e < E; e += stride) {
    int c = ei[E + e];
    if (c >= lo && c < hi) {
      int pos = atomicAdd(&cursor[c], 1);
      csr[pos] = ei[e];
    }
  }
}

// ---------------- fused weight transposes ----------------
__global__ void wt_all_kernel(const float* __restrict__ w0, const float* __restrict__ w1,
                              const float* __restrict__ w2, const float* __restrict__ w3,
                              const float* __restrict__ w4, h16* __restrict__ t0,
                              h16* __restrict__ t1, h16* __restrict__ t2, h16* __restrict__ t3,
                              h16* __restrict__ t4) {
  int gid = blockIdx.x * blockDim.x + threadIdx.x;
  if (gid < 4096) {
    int k = gid / 64, n = gid % 64;
    t0[n * 64 + k] = (h16)w0[gid];
  } else if (gid < 12288) {
    int i = gid - 4096;
    int k = i / 128, n = i % 128;
    t1[n * 64 + k] = (h16)w1[i];
  } else if (gid < 28672) {
    int i = gid - 12288;
    int k = i / 128, n = i % 128;
    t2[n * 128 + k] = (h16)w2[i];
  } else if (gid < 45056) {
    int i = gid - 28672;
    int k = i / 128, n = i % 128;
    t3[n * 128 + k] = (h16)w3[i];
  } else if (gid < 53248) {
    int i = gid - 45056;
    int k = i / 64, n = i % 64;
    t4[n * 128 + k] = (h16)w4[i];
  }
}

// ---------------- MFMA GEMM ----------------
// coefIn (nullable): BN-apply (A,B arrays) on staged input.
// ATT: fused attention coefficients (asrc/adst) from fp32 acc rows; C = N/4.
template <int K, int N, bool STATS, bool ATT>
__global__ void gemm_mfma_kernel(const h16* __restrict__ x, const h16* __restrict__ WT,
                                 const float* __restrict__ bias, const float* __restrict__ coefIn,
                                 h16* __restrict__ out, double* __restrict__ statsOut,
                                 const float* __restrict__ a_src, const float* __restrict__ a_dst,
                                 float* __restrict__ asrcO, float* __restrict__ adstO,
                                 int n_nodes) {
  constexpr int KP = K + 8;
  constexpr int NT = N / 16;
  constexpr int C = N / 4;  // head width for ATT
  __shared__ h16 Ah[128 * KP];
  __shared__ h16 Bs[N * KP];
  __shared__ float sh1[N], sh2[N];
  int tid = threadIdx.x;
  int node0 = blockIdx.x * 128;
  int limit = min(128, n_nodes - node0);
  if (STATS && tid < N) {
    sh1[tid] = 0.f;
    sh2[tid] = 0.f;
  }
  for (int i = tid; i < 128 * (K / 8); i += 256) {
    int row = i / (K / 8), kb = i % (K / 8);
    v8h v = {};
    if (row < limit) {
      v = *(const v8h*)(x + (size_t)(node0 + row) * K + kb * 8);
      if (coefIn) {
#pragma unroll
        for (int j = 0; j < 8; ++j)
          v[j] = (h16)fmaf((float)v[j], coefIn[kb * 8 + j], coefIn[K + kb * 8 + j]);
      }
    }
    *(v8h*)(Ah + row * KP + kb * 8) = v;
  }
  for (int i = tid; i < N * (K / 8); i += 256) {
    int nrow = i / (K / 8), kb = i % (K / 8);
    *(v8h*)(Bs + nrow * KP + kb * 8) = *(const v8h*)(WT + (size_t)nrow * K + kb * 8);
  }
  __syncthreads();

  int w = tid >> 6, lane = tid & 63, quad = lane >> 4, l16 = lane & 15;
  v4f acc[2][NT];
#pragma unroll
  for (int rt = 0; rt < 2; ++rt)
#pragma unroll
    for (int nt = 0; nt < NT; ++nt) acc[rt][nt] = (v4f){0.f, 0.f, 0.f, 0.f};

  int rowb = w * 32;
#pragma unroll
  for (int ks = 0; ks < K / 32; ++ks) {
    v8h a0 = *(const v8h*)(Ah + (rowb + l16) * KP + ks * 32 + quad * 8);
    v8h a1 = *(const v8h*)(Ah + (rowb + 16 + l16) * KP + ks * 32 + quad * 8);
#pragma unroll
    for (int nt = 0; nt < NT; ++nt) {
      v8h b = *(const v8h*)(Bs + (nt * 16 + l16) * KP + ks * 32 + quad * 8);
      acc[0][nt] = __builtin_amdgcn_mfma_f32_16x16x32_f16(a0, b, acc[0][nt], 0, 0, 0);
      acc[1][nt] = __builtin_amdgcn_mfma_f32_16x16x32_f16(a1, b, acc[1][nt], 0, 0, 0);
    }
  }

#pragma unroll
  for (int nt = 0; nt < NT; ++nt) {
    int col = nt * 16 + l16;
    float bv = bias ? bias[col] : 0.f;
    float p1 = 0.f, p2 = 0.f;
#pragma unroll
    for (int rt = 0; rt < 2; ++rt) {
#pragma unroll
      for (int reg = 0; reg < 4; ++reg) {
        int row = rowb + rt * 16 + quad * 4 + reg;
        if (row < limit) {
          float v = acc[rt][nt][reg] + bv;
          out[(size_t)(node0 + row) * N + col] = (h16)v;
          if (STATS) {
            p1 += v;
            p2 = fmaf(v, v, p2);
          }
        }
      }
    }
    if (STATS) {
      atomicAdd(&sh1[col], p1);
      atomicAdd(&sh2[col], p2);
    }
  }

  if (ATT) {
    float wS[NT], wD[NT];
#pragma unroll
    for (int nt = 0; nt < NT; ++nt) {
      int h = (C == 16) ? nt : (nt >> 1);
      int cp = (C == 16) ? l16 : ((nt & 1) * 16 + l16);
      wS[nt] = a_src[h * C + cp];
      wD[nt] = a_dst[h * C + cp];
    }
#pragma unroll
    for (int rt = 0; rt < 2; ++rt) {
#pragma unroll
      for (int reg = 0; reg < 4; ++reg) {
        int row = rowb + rt * 16 + quad * 4 + reg;
        float s0 = 0.f, s1a = 0.f, s2a = 0.f, s3 = 0.f;
        float d0 = 0.f, d1 = 0.f, d2 = 0.f, d3 = 0.f;
#pragma unroll
        for (int nt = 0; nt < NT; ++nt) {
          int h = (C == 16) ? nt : (nt >> 1);
          float v = acc[rt][nt][reg];
          if (h == 0) {
            s0 = fmaf(v, wS[nt], s0);
            d0 = fmaf(v, wD[nt], d0);
          } else if (h == 1) {
            s1a = fmaf(v, wS[nt], s1a);
            d1 = fmaf(v, wD[nt], d1);
          } else if (h == 2) {
            s2a = fmaf(v, wS[nt], s2a);
            d2 = fmaf(v, wD[nt], d2);
          } else {
            s3 = fmaf(v, wS[nt], s3);
            d3 = fmaf(v, wD[nt], d3);
          }
        }
#pragma unroll
        for (int m = 1; m < 16; m <<= 1) {
          s0 += __shfl_xor(s0, m, 64);
          s1a += __shfl_xor(s1a, m, 64);
          s2a += __shfl_xor(s2a, m, 64);
          s3 += __shfl_xor(s3, m, 64);
          d0 += __shfl_xor(d0, m, 64);
          d1 += __shfl_xor(d1, m, 64);
          d2 += __shfl_xor(d2, m, 64);
          d3 += __shfl_xor(d3, m, 64);
        }
        if (row < limit && l16 < 4) {
          float sv = (l16 == 0) ? s0 : (l16 == 1) ? s1a : (l16 == 2) ? s2a : s3;
          float dv = (l16 == 0) ? d0 : (l16 == 1) ? d1 : (l16 == 2) ? d2 : d3;
          asrcO[(node0 + row) * 4 + l16] = sv;
          adstO[(node0 + row) * 4 + l16] = dv;
        }
      }
    }
  }

  if (STATS) {
    __syncthreads();
    double* st = statsOut + (blockIdx.x & (SREP - 1)) * 256;
    if (tid < N) {
      atomicAdd(&st[tid], (double)sh1[tid]);
      atomicAdd(&st[N + tid], (double)sh2[tid]);
    }
  }
}

// ---------------- VALU GEMM (K=16 only) ----------------
template <int K, int DOUT, int MT, bool STATS>
__global__ void gemm_tile_kernel(const h16* __restrict__ x, const float* __restrict__ W,
                                 const float* __restrict__ bias, h16* __restrict__ out,
                                 double* __restrict__ stats, int n_nodes) {
  constexpr int COLG = DOUT / 4;
  constexpr int ROWG = 256 / COLG;
  constexpr int NODES = ROWG * MT;
  constexpr int KP = K + 4;
  __shared__ float xs[NODES * KP];
  __shared__ float sh1[DOUT], sh2[DOUT];
  int tid = threadIdx.x;
  if (STATS && tid < DOUT) {
    sh1[tid] = 0.f;
    sh2[tid] = 0.f;
  }
  int node0 = blockIdx.x * NODES;
  int limit = min(NODES, n_nodes - node0);
  const h16x4* src = (const h16x4*)(x + (size_t)node0 * K);
  int tile_q = (limit * K) >> 2;
  for (int i = tid; i < tile_q; i += 256) {
    h16x4 v = src[i];
    int row = i / (K / 4), cq = i % (K / 4);
    float4 f;
    f.x = (float)v[0];
    f.y = (float)v[1];
    f.z = (float)v[2];
    f.w = (float)v[3];
    *(float4*)(xs + row * KP + cq * 4) = f;
  }
  __syncthreads();
  int cg = tid % COLG, rg = tid / COLG;
  int c0 = cg * 4;
  float acc[MT][4];
#pragma unroll
  for (int m = 0; m < MT; ++m)
#pragma unroll
    for (int i = 0; i < 4; ++i) acc[m][i] = 0.f;

  for (int k4 = 0; k4 < K / 4; ++k4) {
    int k = k4 * 4;
    float4 w0 = *(const float4*)(W + (size_t)(k + 0) * DOUT + c0);
    float4 w1 = *(const float4*)(W + (size_t)(k + 1) * DOUT + c0);
    float4 w2 = *(const float4*)(W + (size_t)(k + 2) * DOUT + c0);
    float4 w3 = *(const float4*)(W + (size_t)(k + 3) * DOUT + c0);
#pragma unroll
    for (int m = 0; m < MT; ++m) {
      float4 xv = *(const float4*)(xs + (rg * MT + m) * KP + k);
      acc[m][0] = fmaf(xv.x, w0.x, acc[m][0]);
      acc[m][1] = fmaf(xv.x, w0.y, acc[m][1]);
      acc[m][2] = fmaf(xv.x, w0.z, acc[m][2]);
      acc[m][3] = fmaf(xv.x, w0.w, acc[m][3]);
      acc[m][0] = fmaf(xv.y, w1.x, acc[m][0]);
      acc[m][1] = fmaf(xv.y, w1.y, acc[m][1]);
      acc[m][2] = fmaf(xv.y, w1.z, acc[m][2]);
      acc[m][3] = fmaf(xv.y, w1.w, acc[m][3]);
      acc[m][0] = fmaf(xv.z, w2.x, acc[m][0]);
      acc[m][1] = fmaf(xv.z, w2.y, acc[m][1]);
      acc[m][2] = fmaf(xv.z, w2.z, acc[m][2]);
      acc[m][3] = fmaf(xv.z, w2.w, acc[m][3]);
      acc[m][0] = fmaf(xv.w, w3.x, acc[m][0]);
      acc[m][1] = fmaf(xv.w, w3.y, acc[m][1]);
      acc[m][2] = fmaf(xv.w, w3.z, acc[m][2]);
      acc[m][3] = fmaf(xv.w, w3.w, acc[m][3]);
    }
  }
  float4 bv = make_float4(0.f, 0.f, 0.f, 0.f);
  if (bias) bv = *(const float4*)(bias + c0);
  float p1[4] = {0.f, 0.f, 0.f, 0.f}, p2[4] = {0.f, 0.f, 0.f, 0.f};
#pragma unroll
  for (int m = 0; m < MT; ++m) {
    int node = node0 + rg * MT + m;
    if (node < n_nodes) {
      float v0 = acc[m][0] + bv.x, v1 = acc[m][1] + bv.y;
      float v2 = acc[m][2] + bv.z, v3 = acc[m][3] + bv.w;
      h16x4 r;
      r[0] = (h16)v0;
      r[1] = (h16)v1;
      r[2] = (h16)v2;
      r[3] = (h16)v3;
      *(h16x4*)(out + (size_t)node * DOUT + c0) = r;
      if (STATS) {
        p1[0] += v0;
        p1[1] += v1;
        p1[2] += v2;
        p1[3] += v3;
        p2[0] = fmaf(v0, v0, p2[0]);
        p2[1] = fmaf(v1, v1, p2[1]);
        p2[2] = fmaf(v2, v2, p2[2]);
        p2[3] = fmaf(v3, v3, p2[3]);
      }
    }
  }
  if (STATS) {
#pragma unroll
    for (int i = 0; i < 4; ++i) {
      atomicAdd(&sh1[c0 + i], p1[i]);
      atomicAdd(&sh2[c0 + i], p2[i]);
    }
    __syncthreads();
    double* st = stats + (blockIdx.x & (SREP - 1)) * 256;
    if (tid < DOUT) {
      atomicAdd(&st[tid], (double)sh1[tid]);
      atomicAdd(&st[DOUT + tid], (double)sh2[tid]);
    }
  }
}

// ---------------- standalone BN stats / coef ----------------
template <int D>
__global__ void bn_stats_kernel(const h16* __restrict__ x, double* __restrict__ stats, int n) {
  int tid = threadIdx.x;
  int c = tid & (D - 1);
  const int rpb = 256 / D;
  float s1 = 0.f, s2 = 0.f;
  for (int r = blockIdx.x * rpb + tid / D; r < n; r += gridDim.x * rpb) {
    float v = (float)x[(size_t)r * D + c];
    s1 += v;
    s2 = fmaf(v, v, s2);
  }
  double* st = stats + (blockIdx.x & (SREP - 1)) * 256;
  atomicAdd(&st[c], (double)s1);
  atomicAdd(&st[D + c], (double)s2);
}

template <int D>
__global__ void bn_coef_kernel(const double* __restrict__ stats, const float* __restrict__ g,
                               const float* __restrict__ b, float* __restrict__ coef, int n) {
  int c = threadIdx.x;
  if (c >= D) return;
  double s1 = 0.0, s2 = 0.0;
#pragma unroll
  for (int r = 0; r < SREP; ++r) {
    s1 += stats[r * 256 + c];
    s2 += stats[r * 256 + D + c];
  }
  double inv_n = 1.0 / (double)n;
  double mu = s1 * inv_n;
  double var = s2 * inv_n - mu * mu;
  float A = (float)(1.0 / sqrt(var + 1e-5)) * g[c];
  coef[c] = A;
  coef[D + c] = b[c] - (float)mu * A;
}

// ---------------- GCN aggregation ----------------
__global__ void gcn_agg16_kernel(const float* __restrict__ h, const int* __restrict__ rowptr,
                                 const int* __restrict__ csr, const float* __restrict__ dis,
                                 h16* __restrict__ out, int n) {
  int wave = (blockIdx.x * blockDim.x + threadIdx.x) >> 6;
  int lane = threadIdx.x & 63;
  if (wave >= n) return;
  int s = rowptr[wave], e = rowptr[wave + 1];
  int q = lane >> 4, c = lane & 15;
  float acc = 0.f;
  for (int k = s + q; k < e; k += 4) {
    int j = csr[k];
    acc = fmaf(dis[j], h[(size_t)j * 16 + c], acc);
  }
  acc += __shfl_xor(acc, 16, 64);
  acc += __shfl_xor(acc, 32, 64);
  if (lane < 16) out[(size_t)wave * 16 + lane] = (h16)(dis[wave] * acc);
}

__global__ void gcn_agg64_kernel(const h16* __restrict__ h, const int* __restrict__ rowptr,
                                 const int* __restrict__ csr, const float* __restrict__ dis,
                                 const float* __restrict__ bias, h16* __restrict__ out, int n) {
  int wave = (blockIdx.x * blockDim.x + threadIdx.x) >> 6;
  int lane = threadIdx.x & 63;
  if (wave >= n) return;
  int s = rfl(rowptr[wave]);
  int e = rfl(rowptr[wave + 1]);
  float a[4] = {0.f, 0.f, 0.f, 0.f};
  int k = s;
  for (; k + 8 <= e; k += 8) {
    int j[8];
    float d[8];
#pragma unroll
    for (int u = 0; u < 8; ++u) j[u] = rfl(csr[k + u]);
#pragma unroll
    for (int u = 0; u < 8; ++u) d[u] = dis[j[u]];
#pragma unroll
    for (int u = 0; u < 8; ++u) {
      const h16* rp = h + (size_t)j[u] * 64;
      a[u & 3] = fmaf(d[u], (float)rp[lane], a[u & 3]);
    }
  }
  for (; k + 4 <= e; k += 4) {
    int j[4];
#pragma unroll
    for (int u = 0; u < 4; ++u) j[u] = rfl(csr[k + u]);
#pragma unroll
    for (int u = 0; u < 4; ++u) {
      const h16* rp = h + (size_t)j[u] * 64;
      a[u] = fmaf(dis[j[u]], (float)rp[lane], a[u]);
    }
  }
  for (; k < e; ++k) {
    int j0 = rfl(csr[k]);
    const h16* rp = h + (size_t)j0 * 64;
    a[0] = fmaf(dis[j0], (float)rp[lane], a[0]);
  }
  float b0 = bias ? bias[lane] : 0.f;
  out[(size_t)wave * 64 + lane] = (h16)fmaf(dis[wave], (a[0] + a[1]) + (a[2] + a[3]), b0);
}

template <bool COEF>
__global__ void gcn_agg128_kernel(const h16* __restrict__ h, const int* __restrict__ rowptr,
                                  const int* __restrict__ csr, const float* __restrict__ dis,
                                  const float* __restrict__ coef, h16* __restrict__ out, int n) {
  int wave = (blockIdx.x * blockDim.x + threadIdx.x) >> 6;
  int lane = threadIdx.x & 63;
  if (wave >= n) return;
  int s = rfl(rowptr[wave]);
  int e = rfl(rowptr[wave + 1]);
  int c2 = lane * 2;
  float2 A2 = make_float2(0.f, 0.f), B2 = make_float2(0.f, 0.f);
  if (COEF) {
    A2 = *(const float2*)(coef + c2);
    B2 = *(const float2*)(coef + 128 + c2);
  }
  float a0[4] = {0.f, 0.f, 0.f, 0.f};
  float a1[4] = {0.f, 0.f, 0.f, 0.f};
  int k = s;
  for (; k + 8 <= e; k += 8) {
    int j[8];
    float d[8];
#pragma unroll
    for (int u = 0; u < 8; ++u) j[u] = rfl(csr[k + u]);
#pragma unroll
    for (int u = 0; u < 8; ++u) d[u] = dis[j[u]];
#pragma unroll
    for (int u = 0; u < 8; ++u) {
      const h16* rp = h + (size_t)j[u] * 128;
      h16x2 v = *(const h16x2*)(rp + c2);
      float f0 = (float)v[0], f1 = (float)v[1];
      if (COEF) {
        f0 = lrelu(fmaf(f0, A2.x, B2.x));
        f1 = lrelu(fmaf(f1, A2.y, B2.y));
      }
      a0[u & 3] = fmaf(d[u], f0, a0[u & 3]);
      a1[u & 3] = fmaf(d[u], f1, a1[u & 3]);
    }
  }
  for (; k < e; ++k) {
    int j0 = rfl(csr[k]);
    float d0 = dis[j0];
    const h16* rp = h + (size_t)j0 * 128;
    h16x2 v = *(const h16x2*)(rp + c2);
    float f0 = (float)v[0], f1 = (float)v[1];
    if (COEF) {
      f0 = lrelu(fmaf(f0, A2.x, B2.x));
      f1 = lrelu(fmaf(f1, A2.y, B2.y));
    }
    a0[0] = fmaf(d0, f0, a0[0]);
    a1[0] = fmaf(d0, f1, a1[0]);
  }
  float di = dis[wave];
  h16x2 r;
  r[0] = (h16)(di * ((a0[0] + a0[1]) + (a0[2] + a0[3])));
  r[1] = (h16)(di * ((a1[0] + a1[1]) + (a1[2] + a1[3])));
  *(h16x2*)(out + (size_t)wave * 128 + c2) = r;
}

// ---------------- GAT ----------------
// Dedicated softmax-coef pass (r11 lesson: keep the asrc table L2-resident here).
__global__ void edge_coef_kernel(const int* __restrict__ rowptr, const int* __restrict__ csr,
                                 const float* __restrict__ asrc, const float* __restrict__ adst,
                                 float* __restrict__ exbuf, float* __restrict__ dinv, int n) {
  int wave = (blockIdx.x * blockDim.x + threadIdx.x) >> 6;
  int lane = threadIdx.x & 63;
  if (wave >= n) return;
  int h = lane & 3, es = lane >> 2;
  float ad = adst[wave * 4 + h];
  int s = rowptr[wave], e = rowptr[wave + 1];
  float den = 0.f;
  for (int k = s + es; k < e; k += 16) {
    int j = csr[k];
    float v = __expf(lrelu(asrc[j * 4 + h] + ad));
    exbuf[(size_t)k * 4 + h] = v;
    den += v;
  }
  den += __shfl_xor(den, 4, 64);
  den += __shfl_xor(den, 8, 64);
  den += __shfl_xor(den, 16, 64);
  den += __shfl_xor(den, 32, 64);
  if (lane < 4) dinv[wave * 4 + h] = 1.0f / den;
}

// D=64,C=16: residual BN-apply fused (rescoef array).
__global__ void gat_agg64_kernel(const h16* __restrict__ h2, const int* __restrict__ rowptr,
                                 const int* __restrict__ csr, const float* __restrict__ exbuf,
                                 const float* __restrict__ dinv, const float* __restrict__ bias,
                                 const h16* __restrict__ xres, const float* __restrict__ rescoef,
                                 h16* __restrict__ out, int n) {
  int wave = (blockIdx.x * blockDim.x + threadIdx.x) >> 6;
  int lane = threadIdx.x & 63;
  if (wave >= n) return;
  int head = lane >> 4;
  int s = rfl(rowptr[wave]);
  int e = rfl(rowptr[wave + 1]);
  float a[4] = {0.f, 0.f, 0.f, 0.f};
  int k = s;
  for (; k + 8 <= e; k += 8) {
    int j[8];
    float ex[8];
#pragma unroll
    for (int u = 0; u < 8; ++u) {
      j[u] = rfl(csr[k + u]);
      ex[u] = exbuf[(size_t)(k + u) * 4 + head];
    }
#pragma unroll
    for (int u = 0; u < 8; ++u) {
      const h16* rp = h2 + (size_t)j[u] * 64;
      a[u & 3] = fmaf(ex[u], (float)rp[lane], a[u & 3]);
    }
  }
  for (; k + 4 <= e; k += 4) {
    int j[4];
    float ex[4];
#pragma unroll
    for (int u = 0; u < 4; ++u) {
      j[u] = rfl(csr[k + u]);
      ex[u] = exbuf[(size_t)(k + u) * 4 + head];
    }
#pragma unroll
    for (int u = 0; u < 4; ++u) {
      const h16* rp = h2 + (size_t)j[u] * 64;
      a[u] = fmaf(ex[u], (float)rp[lane], a[u]);
    }
  }
  for (; k < e; ++k) {
    int j0 = rfl(csr[k]);
    const h16* rp = h2 + (size_t)j0 * 64;
    a[0] = fmaf(exbuf[(size_t)k * 4 + head], (float)rp[lane], a[0]);
  }
  float dv = dinv[wave * 4 + head];
  size_t base = (size_t)wave * 64;
  float xv = fmaf((float)xres[base + lane], rescoef[lane], rescoef[64 + lane]);
  float v0 = ((a[0] + a[1]) + (a[2] + a[3])) * dv + bias[lane] + xv;
  out[base + lane] = (h16)lrelu(v0);
}

// D=128,C=32: residual BN-apply fused (rescoef array).
__global__ void gat_agg128_kernel(const h16* __restrict__ h2, const int* __restrict__ rowptr,
                                  const int* __restrict__ csr, const float* __restrict__ exbuf,
                                  const float* __restrict__ dinv, const float* __restrict__ bias,
                                  const h16* __restrict__ xres, const float* __restrict__ rescoef,
                                  h16* __restrict__ out, int n) {
  int wave = (blockIdx.x * blockDim.x + threadIdx.x) >> 6;
  int lane = threadIdx.x & 63;
  if (wave >= n) return;
  int head = lane >> 4;
  int c2 = lane * 2;
  int s = rfl(rowptr[wave]);
  int e = rfl(rowptr[wave + 1]);
  float a0[4] = {0.f, 0.f, 0.f, 0.f};
  float a1[4] = {0.f, 0.f, 0.f, 0.f};
  int k = s;
  for (; k + 8 <= e; k += 8) {
    int j[8];
    float ex[8];
#pragma unroll
    for (int u = 0; u < 8; ++u) {
      j[u] = rfl(csr[k + u]);
      ex[u] = exbuf[(size_t)(k + u) * 4 + head];
    }
#pragma unroll
    for (int u = 0; u < 8; ++u) {
      const h16* rp = h2 + (size_t)j[u] * 128;
      h16x2 v = *(const h16x2*)(rp + c2);
      a0[u & 3] = fmaf(ex[u], (float)v[0], a0[u & 3]);
      a1[u & 3] = fmaf(ex[u], (float)v[1], a1[u & 3]);
    }
  }
  for (; k + 4 <= e; k += 4) {
    int j[4];
    float ex[4];
#pragma unroll
    for (int u = 0; u < 4; ++u) {
      j[u] = rfl(csr[k + u]);
      ex[u] = exbuf[(size_t)(k + u) * 4 + head];
    }
#pragma unroll
    for (int u = 0; u < 4; ++u) {
      const h16* rp = h2 + (size_t)j[u] * 128;
      h16x2 v = *(const h16x2*)(rp + c2);
      a0[u] = fmaf(ex[u], (float)v[0], a0[u]);
      a1[u] = fmaf(ex[u], (float)v[1], a1[u]);
    }
  }
  for (; k < e; ++k) {
    int j0 = rfl(csr[k]);
    float e0 = exbuf[(size_t)k * 4 + head];
    const h16* rp = h2 + (size_t)j0 * 128;
    h16x2 v = *(const h16x2*)(rp + c2);
    a0[0] = fmaf(e0, (float)v[0], a0[0]);
    a1[0] = fmaf(e0, (float)v[1], a1[0]);
  }
  float dv = dinv[wave * 4 + head];
  float2 b2 = *(const float2*)(bias + c2);
  float2 A2 = *(const float2*)(rescoef + c2);
  float2 B2 = *(const float2*)(rescoef + 128 + c2);
  size_t base = (size_t)wave * 128;
  h16x2 xr = *(const h16x2*)(xres + base + c2);
  float xr0 = fmaf((float)xr[0], A2.x, B2.x);
  float xr1 = fmaf((float)xr[1], A2.y, B2.y);
  float v0 = ((a0[0] + a0[1]) + (a0[2] + a0[3])) * dv + b2.x + xr0;
  float v1 = ((a1[0] + a1[1]) + (a1[2] + a1[3])) * dv + b2.y + xr1;
  h16x2 r;
  r[0] = (h16)lrelu(v0);
  r[1] = (h16)lrelu(v1);
  *(h16x2*)(out + base + c2) = r;
}

// ---------------- global mean pool (inline bounds + coef array) ----------------
__global__ void pool_kernel(const h16* __restrict__ x, const int* __restrict__ batch,
                            const float* __restrict__ coef, float* __restrict__ out, int n) {
  __shared__ float sh[4][64];
  __shared__ int sb[2];
  int tid = threadIdx.x;
  int gid = blockIdx.x;
  if (tid < 2) {  // lower_bound(batch, gid + tid)
    int key = gid + tid;
    int lo = 0, hi = n;
    while (lo < hi) {
      int mid = (lo + hi) >> 1;
      if (batch[mid] < key)
        lo = mid + 1;
      else
        hi = mid;
    }
    sb[tid] = lo;
  }
  __syncthreads();
  int s = sb[0], e = sb[1];
  int lane = tid & 63, w = tid >> 6;
  float acc = 0.f;
  for (int r = s + w; r < e; r += 4) acc += (float)x[(size_t)r * 64 + lane];
  sh[w][lane] = acc;
  __syncthreads();
  if (w == 0) {
    float t = sh[0][lane] + sh[1][lane] + sh[2][lane] + sh[3][lane];
    float cntf = (float)(e - s);
    out[(gid << 6) + lane] = fmaf(coef[lane], t, coef[64 + lane] * cntf) / fmaxf(cntf, 1.0f);
  }
}

// ---------------- host ----------------
extern "C" void kernel_launch(void* const* d_in, const int* in_sizes, int n_in, void* d_out,
                              int out_size, void* d_ws, size_t ws_size, hipStream_t stream) {
  const float* x_in = (const float*)d_in[0];
  const int* ei = (const int*)d_in[1];
  const int* batch = (const int*)d_in[2];
  const float* gcn_w[4] = {(const float*)d_in[3], (const float*)d_in[7], (const float*)d_in[11],
                           (const float*)d_in[15]};
  const float* gcn_b[4] = {(const float*)d_in[4], (const float*)d_in[8], (const float*)d_in[12],
                           (const float*)d_in[16]};
  const float* bn_g[4] = {(const float*)d_in[5], (const float*)d_in[9], (const float*)d_in[13],
                          (const float*)d_in[17]};
  const float* bn_b[4] = {(const float*)d_in[6], (const float*)d_in[10], (const float*)d_in[14],
                          (const float*)d_in[18]};
  const float* gat_w0 = (const float*)d_in[19];
  const float* gat_as0 = (const float*)d_in[20];
  const float* gat_ad0 = (const float*)d_in[21];
  const float* gat_b0 = (const float*)d_in[22];
  const float* gat_w2 = (const float*)d_in[23];
  const float* gat_as2 = (const float*)d_in[24];
  const float* gat_ad2 = (const float*)d_in[25];
  const float* gat_b2 = (const float*)d_in[26];

  const int N = in_sizes[2];      // 100000
  const int E = in_sizes[1] / 2;  // 1600000

  char* wp = (char*)d_ws;
  auto alloc = [&](size_t bytes) -> void* {
    void* p = (void*)wp;
    wp += (bytes + 255) & ~(size_t)255;
    return p;
  };
  double* statsAll = (double*)alloc(4 * SREP * 256 * sizeof(double));
  float* coefAll = (float*)alloc(4 * 256 * sizeof(float));
  int* rowptr = (int*)alloc((size_t)(N + 1) * 4);
  int* cursor = (int*)alloc((size_t)N * 4);
  int* partial = (int*)alloc(256 * sizeof(int));
  int* csr = (int*)alloc((size_t)(N + E) * 4);
  float* dis = (float*)alloc((size_t)N * 4);
  h16* bufA = (h16*)alloc((size_t)N * 128 * 2);
  h16* bufB = (h16*)alloc((size_t)N * 128 * 2);
  h16* bufC = (h16*)alloc((size_t)N * 128 * 2);
  float* attS = (float*)alloc((size_t)N * 4 * 4);
  float* attD = (float*)alloc((size_t)N * 4 * 4);
  float* exbuf = (float*)alloc((size_t)(N + E) * 4 * 4);
  float* dinv = (float*)alloc((size_t)N * 4 * 4);
  h16* wt0 = (h16*)alloc(64 * 64 * 2);
  h16* wt1 = (h16*)alloc(64 * 128 * 2);
  h16* wt2 = (h16*)alloc(128 * 128 * 2);
  h16* wt3 = (h16*)alloc(128 * 128 * 2);
  h16* wt4 = (h16*)alloc(128 * 64 * 2);
  if ((size_t)(wp - (char*)d_ws) > ws_size) return;

  double* stats0 = statsAll;
  double* stats1 = statsAll + SREP * 256;
  double* stats2 = statsAll + 2 * SREP * 256;
  double* stats3 = statsAll + 3 * SREP * 256;
  float* coef0 = coefAll;
  float* coef1 = coefAll + 256;
  float* coef2 = coefAll + 512;
  float* coef3 = coefAll + 768;

  const int B = 256;
  auto cd = [](int a, int b) { return (a + b - 1) / b; };
  const int scan_blocks = cd(N, SCAN_CHUNK);
  const int nbkt = cd(N, XCDS);

  // --- zero + transposes + CSR build ---
  zero_f32_kernel<<<cd(4 * SREP * 512, B), B, 0, stream>>>((float*)statsAll, 4 * SREP * 512);
  wt_all_kernel<<<cd(53248, B), B, 0, stream>>>(gat_w0, gcn_w[1], gcn_w[2], gat_w2, gcn_w[3], wt0,
                                                wt1, wt2, wt3, wt4);
  init_counts_kernel<<<cd(N, B), B, 0, stream>>>(cursor, N);
  count_edges_kernel<<<XCDS * 512, B, 0, stream>>>(ei, cursor, E, nbkt);
  block_sum_kernel<<<scan_blocks, B, 0, stream>>>(cursor, partial, N);
  partial_scan_kernel<<<1, B, 0, stream>>>(partial, rowptr, scan_blocks, N);
  chunk_scan_kernel<<<scan_blocks, B, 0, stream>>>(cursor, partial, rowptr, N);
  finalize_csr_kernel<<<cd(N, B), B, 0, stream>>>(rowptr, dis, cursor, csr, N);
  fill_edges_kernel<<<XCDS * 512, B, 0, stream>>>(ei, cursor, csr, E, nbkt);

  // ---- Layer 0: GCN 16->64 (agg16 -> VALU gemm w/ stats), BN-coef ----
  gcn_agg16_kernel<<<cd(N * 64, B), B, 0, stream>>>(x_in, rowptr, csr, dis, bufB, N);
  gemm_tile_kernel<16, 64, 8, true>
      <<<cd(N, 128), B, 0, stream>>>(bufB, gcn_w[0], gcn_b[0], bufC, stats0, N);
  bn_coef_kernel<64><<<1, 64, 0, stream>>>(stats0, bn_g[0], bn_b[0], coef0, N);
  // GAT0: MFMA gemm (coef0 on input + fused att) -> edge_coef -> gat (coef0 on residual)
  gemm_mfma_kernel<64, 64, false, true><<<cd(N, 128), B, 0, stream>>>(
      bufC, wt0, nullptr, coef0, bufB, nullptr, gat_as0, gat_ad0, attS, attD, N);
  edge_coef_kernel<<<cd(N * 64, B), B, 0, stream>>>(rowptr, csr, attS, attD, exbuf, dinv, N);
  gat_agg64_kernel<<<cd(N * 64, B), B, 0, stream>>>(bufB, rowptr, csr, exbuf, dinv, gat_b0, bufC,
                                                    coef0, bufA, N);

  // ---- Layer 1: GCN 64->128 (agg64 -> MFMA gemm w/ stats), BN-coef ----
  gcn_agg64_kernel<<<cd(N * 64, B), B, 0, stream>>>(bufA, rowptr, csr, dis, nullptr, bufB, N);
  gemm_mfma_kernel<64, 128, true, false><<<cd(N, 128), B, 0, stream>>>(
      bufB, wt1, gcn_b[1], nullptr, bufC, stats1, nullptr, nullptr, nullptr, nullptr, N);
  bn_coef_kernel<128><<<1, 128, 0, stream>>>(stats1, bn_g[1], bn_b[1], coef1, N);

  // ---- Layer 2: GCN 128->128 (agg applies coef1+lrelu) -> MFMA gemm w/ stats, BN-coef ----
  gcn_agg128_kernel<true><<<cd(N * 64, B), B, 0, stream>>>(bufC, rowptr, csr, dis, coef1, bufB, N);
  gemm_mfma_kernel<128, 128, true, false><<<cd(N, 128), B, 0, stream>>>(
      bufB, wt2, gcn_b[2], nullptr, bufA, stats2, nullptr, nullptr, nullptr, nullptr, N);
  bn_coef_kernel<128><<<1, 128, 0, stream>>>(stats2, bn_g[2], bn_b[2], coef2, N);
  // GAT2: MFMA gemm (coef2 on input + fused att) -> edge_coef -> gat (coef2 on residual)
  gemm_mfma_kernel<128, 128, false, true><<<cd(N, 128), B, 0, stream>>>(
      bufA, wt3, nullptr, coef2, bufB, nullptr, gat_as2, gat_ad2, attS, attD, N);
  edge_coef_kernel<<<cd(N * 64, B), B, 0, stream>>>(rowptr, csr, attS, attD, exbuf, dinv, N);
  gat_agg128_kernel<<<cd(N * 64, B), B, 0, stream>>>(bufB, rowptr, csr, exbuf, dinv, gat_b2, bufA,
                                                     coef2, bufC, N);

  // ---- Layer 3: GCN 128->64 (MFMA gemm -> agg64 w/ bias), stats, BN-coef ----
  gemm_mfma_kernel<128, 64, false, false><<<cd(N, 128), B, 0, stream>>>(
      bufC, wt4, nullptr, nullptr, bufB, nullptr, nullptr, nullptr, nullptr, nullptr, N);
  gcn_agg64_kernel<<<cd(N * 64, B), B, 0, stream>>>(bufB, rowptr, csr, dis, gcn_b[3], bufA, N);
  bn_stats_kernel<64><<<256, 256, 0, stream>>>(bufA, stats3, N);
  bn_coef_kernel<64><<<1, 64, 0, stream>>>(stats3, bn_g[3], bn_b[3], coef3, N);

  // ---- global mean pool (inline bounds + coef3) ----
  pool_kernel<<<GRAPHS, 256, 0, stream>>>(bufA, batch, coef3, (float*)d_out, N);
}

// Round 16
// 907.717 us; speedup vs baseline: 1.0163x; 1.0115x over previous
//
#include <hip/hip_runtime.h>

static constexpr int GRAPHS = 256;
static constexpr int SCAN_CHUNK = 1024;
static constexpr int XCDS = 8;
static constexpr int SREP = 8;  // stats replicas (atomic de-contention)

typedef _Float16 h16;
typedef _Float16 h16x2 __attribute__((ext_vector_type(2)));
typedef _Float16 h16x4 __attribute__((ext_vector_type(4)));
typedef _Float16 v8h __attribute__((ext_vector_type(8)));
typedef float v4f __attribute__((ext_vector_type(4)));

__device__ __forceinline__ float lrelu(float v) { return fmaxf(v, 0.2f * v); }
__device__ __forceinline__ int rfl(int v) { return __builtin_amdgcn_readfirstlane(v); }

// ---------------- utility ----------------
__global__ void zero_f32_kernel(float* __restrict__ p, int n) {
  int i = blockIdx.x * blockDim.x + threadIdx.x;
  if (i < n) p[i] = 0.0f;
}

// ---------------- CSR build ----------------
__global__ void init_counts_kernel(int* __restrict__ cnt, int n) {
  int i = blockIdx.x * blockDim.x + threadIdx.x;
  if (i < n) cnt[i] = 1;  // self loop
}

// XCD-bucketed count: bucket p's counter window stays in one XCD's L2.
__global__ void count_edges_kernel(const int* __restrict__ ei, int* __restrict__ cnt, int E,
                                   int nb) {
  int p = blockIdx.x & (XCDS - 1);
  int lo = p * nb, hi = lo + nb;
  int nchunks = gridDim.x >> 3;
  int chunk = blockIdx.x >> 3;
  int stride = nchunks * blockDim.x;
  for (int e = chunk * blockDim.x + threadIdx.x; e < E; e += stride) {
    int c = ei[E + e];
    if (c >= lo && c < hi) atomicAdd(&cnt[c], 1);
  }
}

__global__ void block_sum_kernel(const int* __restrict__ counts, int* __restrict__ partial,
                                 int n) {
  __shared__ int sh[256];
  int base = blockIdx.x * SCAN_CHUNK;
  int t = threadIdx.x;
  int lim = min(base + SCAN_CHUNK, n);
  int s = 0;
  for (int i = base + t; i < lim; i += 256) s += counts[i];
  sh[t] = s;
  __syncthreads();
  for (int off = 128; off > 0; off >>= 1) {
    if (t < off) sh[t] += sh[t + off];
    __syncthreads();
  }
  if (t == 0) partial[blockIdx.x] = sh[0];
}

__global__ void partial_scan_kernel(int* __restrict__ partial, int* __restrict__ rowptr,
                                    int nblocks, int n) {
  __shared__ int sh[256];
  int t = threadIdx.x;
  int v = (t < nblocks) ? partial[t] : 0;
  sh[t] = v;
  __syncthreads();
  for (int off = 1; off < 256; off <<= 1) {
    int u = (t >= off) ? sh[t - off] : 0;
    __syncthreads();
    sh[t] += u;
    __syncthreads();
  }
  if (t < nblocks) partial[t] = sh[t] - v;
  if (t == 255) rowptr[n] = sh[255];
}

__global__ void chunk_scan_kernel(const int* __restrict__ counts, const int* __restrict__ partial,
                                  int* __restrict__ rowptr, int n) {
  __shared__ int sh[256];
  int base = blockIdx.x * SCAN_CHUNK;
  int t = threadIdx.x;
  int i0 = base + t * 4;
  int c0 = 0, c1 = 0, c2 = 0, c3 = 0;
  if (i0 + 3 < n) {
    int4 c = *(const int4*)(counts + i0);
    c0 = c.x;
    c1 = c.y;
    c2 = c.z;
    c3 = c.w;
  } else {
    if (i0 < n) c0 = counts[i0];
    if (i0 + 1 < n) c1 = counts[i0 + 1];
    if (i0 + 2 < n) c2 = counts[i0 + 2];
  }
  int tot = c0 + c1 + c2 + c3;
  sh[t] = tot;
  __syncthreads();
  for (int off = 1; off < 256; off <<= 1) {
    int u = (t >= off) ? sh[t - off] : 0;
    __syncthreads();
    sh[t] += u;
    __syncthreads();
  }
  int run = partial[blockIdx.x] + sh[t] - tot;
  if (i0 < n) { rowptr[i0] = run; run += c0; }
  if (i0 + 1 < n) { rowptr[i0 + 1] = run; run += c1; }
  if (i0 + 2 < n) { rowptr[i0 + 2] = run; run += c2; }
  if (i0 + 3 < n) { rowptr[i0 + 3] = run; }
}

__global__ void finalize_csr_kernel(const int* __restrict__ rowptr, float* __restrict__ dis,
                                    int* __restrict__ cursor, int* __restrict__ csr, int n) {
  int i = blockIdx.x * blockDim.x + threadIdx.x;
  if (i >= n) return;
  int s = rowptr[i], e = rowptr[i + 1];
  dis[i] = rsqrtf((float)(e - s));
  csr[s] = i;
  cursor[i] = s + 1;
}

__global__ void fill_edges_kernel(const int* __restrict__ ei, int* __restrict__ cursor,
                                  int* __restrict__ csr, int E, int nb) {
  int p = blockIdx.x & (XCDS - 1);
  int lo = p * nb, hi = lo + nb;
  int nchunks = gridDim.x >> 3;
  int chunk = blockIdx.x >> 3;
  int stride = nchunks * blockDim.x;
  for (int e = chunk * blockDim.x + threadIdx.x; e < E; e += stride) {
    int c = ei[E + e];
    if (c >= lo && c < hi) {
      int pos = atomicAdd(&cursor[c], 1);
      csr[pos] = ei[e];
    }
  }
}

// ---------------- fused weight transposes ----------------
__global__ void wt_all_kernel(const float* __restrict__ w0, const float* __restrict__ w1,
                              const float* __restrict__ w2, const float* __restrict__ w3,
                              const float* __restrict__ w4, h16* __restrict__ t0,
                              h16* __restrict__ t1, h16* __restrict__ t2, h16* __restrict__ t3,
                              h16* __restrict__ t4) {
  int gid = blockIdx.x * blockDim.x + threadIdx.x;
  if (gid < 4096) {
    int k = gid / 64, n = gid % 64;
    t0[n * 64 + k] = (h16)w0[gid];
  } else if (gid < 12288) {
    int i = gid - 4096;
    int k = i / 128, n = i % 128;
    t1[n * 64 + k] = (h16)w1[i];
  } else if (gid < 28672) {
    int i = gid - 12288;
    int k = i / 128, n = i % 128;
    t2[n * 128 + k] = (h16)w2[i];
  } else if (gid < 45056) {
    int i = gid - 28672;
    int k = i / 128, n = i % 128;
    t3[n * 128 + k] = (h16)w3[i];
  } else if (gid < 53248) {
    int i = gid - 45056;
    int k = i / 64, n = i % 64;
    t4[n * 128 + k] = (h16)w4[i];
  }
}

// ---------------- MFMA GEMM (verified layouts, learn_hip m89/m91) ----------------
template <int K, int N, bool STATS>
__global__ void gemm_mfma_kernel(const h16* __restrict__ x, const h16* __restrict__ WT,
                                 const float* __restrict__ bias, const float* __restrict__ coefIn,
                                 h16* __restrict__ out, double* __restrict__ stats, int n_nodes) {
  constexpr int KP = K + 8;
  constexpr int NT = N / 16;
  __shared__ h16 Ah[128 * KP];
  __shared__ h16 Bs[N * KP];
  __shared__ float sh1[N], sh2[N];
  int tid = threadIdx.x;
  int node0 = blockIdx.x * 128;
  int limit = min(128, n_nodes - node0);
  if (STATS && tid < N) {
    sh1[tid] = 0.f;
    sh2[tid] = 0.f;
  }
  for (int i = tid; i < 128 * (K / 8); i += 256) {
    int row = i / (K / 8), kb = i % (K / 8);
    v8h v = {};
    if (row < limit) {
      v = *(const v8h*)(x + (size_t)(node0 + row) * K + kb * 8);
      if (coefIn) {
#pragma unroll
        for (int j = 0; j < 8; ++j)
          v[j] = (h16)fmaf((float)v[j], coefIn[kb * 8 + j], coefIn[K + kb * 8 + j]);
      }
    }
    *(v8h*)(Ah + row * KP + kb * 8) = v;
  }
  for (int i = tid; i < N * (K / 8); i += 256) {
    int nrow = i / (K / 8), kb = i % (K / 8);
    *(v8h*)(Bs + nrow * KP + kb * 8) = *(const v8h*)(WT + (size_t)nrow * K + kb * 8);
  }
  __syncthreads();

  int w = tid >> 6, lane = tid & 63, quad = lane >> 4, l16 = lane & 15;
  v4f acc[2][NT];
#pragma unroll
  for (int rt = 0; rt < 2; ++rt)
#pragma unroll
    for (int nt = 0; nt < NT; ++nt) acc[rt][nt] = (v4f){0.f, 0.f, 0.f, 0.f};

  int rowb = w * 32;
#pragma unroll
  for (int ks = 0; ks < K / 32; ++ks) {
    v8h a0 = *(const v8h*)(Ah + (rowb + l16) * KP + ks * 32 + quad * 8);
    v8h a1 = *(const v8h*)(Ah + (rowb + 16 + l16) * KP + ks * 32 + quad * 8);
#pragma unroll
    for (int nt = 0; nt < NT; ++nt) {
      v8h b = *(const v8h*)(Bs + (nt * 16 + l16) * KP + ks * 32 + quad * 8);
      acc[0][nt] = __builtin_amdgcn_mfma_f32_16x16x32_f16(a0, b, acc[0][nt], 0, 0, 0);
      acc[1][nt] = __builtin_amdgcn_mfma_f32_16x16x32_f16(a1, b, acc[1][nt], 0, 0, 0);
    }
  }

#pragma unroll
  for (int nt = 0; nt < NT; ++nt) {
    int col = nt * 16 + l16;
    float bv = bias ? bias[col] : 0.f;
    float p1 = 0.f, p2 = 0.f;
#pragma unroll
    for (int rt = 0; rt < 2; ++rt) {
#pragma unroll
      for (int reg = 0; reg < 4; ++reg) {
        int row = rowb + rt * 16 + quad * 4 + reg;
        if (row < limit) {
          float v = acc[rt][nt][reg] + bv;
          out[(size_t)(node0 + row) * N + col] = (h16)v;
          if (STATS) {
            p1 += v;
            p2 = fmaf(v, v, p2);
          }
        }
      }
    }
    if (STATS) {
      atomicAdd(&sh1[col], p1);
      atomicAdd(&sh2[col], p2);
    }
  }
  if (STATS) {
    __syncthreads();
    double* st = stats + (blockIdx.x & (SREP - 1)) * 256;
    if (tid < N) {
      atomicAdd(&st[tid], (double)sh1[tid]);
      atomicAdd(&st[N + tid], (double)sh2[tid]);
    }
  }
}

// ---------------- VALU GEMM (K=16 only) ----------------
template <int K, int DOUT, int MT, bool STATS>
__global__ void gemm_tile_kernel(const h16* __restrict__ x, const float* __restrict__ W,
                                 const float* __restrict__ bias, h16* __restrict__ out,
                                 double* __restrict__ stats, int n_nodes) {
  constexpr int COLG = DOUT / 4;
  constexpr int ROWG = 256 / COLG;
  constexpr int NODES = ROWG * MT;
  constexpr int KP = K + 4;
  __shared__ float xs[NODES * KP];
  __shared__ float sh1[DOUT], sh2[DOUT];
  int tid = threadIdx.x;
  if (STATS && tid < DOUT) {
    sh1[tid] = 0.f;
    sh2[tid] = 0.f;
  }
  int node0 = blockIdx.x * NODES;
  int limit = min(NODES, n_nodes - node0);
  const h16x4* src = (const h16x4*)(x + (size_t)node0 * K);
  int tile_q = (limit * K) >> 2;
  for (int i = tid; i < tile_q; i += 256) {
    h16x4 v = src[i];
    int row = i / (K / 4), cq = i % (K / 4);
    float4 f;
    f.x = (float)v[0];
    f.y = (float)v[1];
    f.z = (float)v[2];
    f.w = (float)v[3];
    *(float4*)(xs + row * KP + cq * 4) = f;
  }
  __syncthreads();
  int cg = tid % COLG, rg = tid / COLG;
  int c0 = cg * 4;
  float acc[MT][4];
#pragma unroll
  for (int m = 0; m < MT; ++m)
#pragma unroll
    for (int i = 0; i < 4; ++i) acc[m][i] = 0.f;

  for (int k4 = 0; k4 < K / 4; ++k4) {
    int k = k4 * 4;
    float4 w0 = *(const float4*)(W + (size_t)(k + 0) * DOUT + c0);
    float4 w1 = *(const float4*)(W + (size_t)(k + 1) * DOUT + c0);
    float4 w2 = *(const float4*)(W + (size_t)(k + 2) * DOUT + c0);
    float4 w3 = *(const float4*)(W + (size_t)(k + 3) * DOUT + c0);
#pragma unroll
    for (int m = 0; m < MT; ++m) {
      float4 xv = *(const float4*)(xs + (rg * MT + m) * KP + k);
      acc[m][0] = fmaf(xv.x, w0.x, acc[m][0]);
      acc[m][1] = fmaf(xv.x, w0.y, acc[m][1]);
      acc[m][2] = fmaf(xv.x, w0.z, acc[m][2]);
      acc[m][3] = fmaf(xv.x, w0.w, acc[m][3]);
      acc[m][0] = fmaf(xv.y, w1.x, acc[m][0]);
      acc[m][1] = fmaf(xv.y, w1.y, acc[m][1]);
      acc[m][2] = fmaf(xv.y, w1.z, acc[m][2]);
      acc[m][3] = fmaf(xv.y, w1.w, acc[m][3]);
      acc[m][0] = fmaf(xv.z, w2.x, acc[m][0]);
      acc[m][1] = fmaf(xv.z, w2.y, acc[m][1]);
      acc[m][2] = fmaf(xv.z, w2.z, acc[m][2]);
      acc[m][3] = fmaf(xv.z, w2.w, acc[m][3]);
      acc[m][0] = fmaf(xv.w, w3.x, acc[m][0]);
      acc[m][1] = fmaf(xv.w, w3.y, acc[m][1]);
      acc[m][2] = fmaf(xv.w, w3.z, acc[m][2]);
      acc[m][3] = fmaf(xv.w, w3.w, acc[m][3]);
    }
  }
  float4 bv = make_float4(0.f, 0.f, 0.f, 0.f);
  if (bias) bv = *(const float4*)(bias + c0);
  float p1[4] = {0.f, 0.f, 0.f, 0.f}, p2[4] = {0.f, 0.f, 0.f, 0.f};
#pragma unroll
  for (int m = 0; m < MT; ++m) {
    int node = node0 + rg * MT + m;
    if (node < n_nodes) {
      float v0 = acc[m][0] + bv.x, v1 = acc[m][1] + bv.y;
      float v2 = acc[m][2] + bv.z, v3 = acc[m][3] + bv.w;
      h16x4 r;
      r[0] = (h16)v0;
      r[1] = (h16)v1;
      r[2] = (h16)v2;
      r[3] = (h16)v3;
      *(h16x4*)(out + (size_t)node * DOUT + c0) = r;
      if (STATS) {
        p1[0] += v0;
        p1[1] += v1;
        p1[2] += v2;
        p1[3] += v3;
        p2[0] = fmaf(v0, v0, p2[0]);
        p2[1] = fmaf(v1, v1, p2[1]);
        p2[2] = fmaf(v2, v2, p2[2]);
        p2[3] = fmaf(v3, v3, p2[3]);
      }
    }
  }
  if (STATS) {
#pragma unroll
    for (int i = 0; i < 4; ++i) {
      atomicAdd(&sh1[c0 + i], p1[i]);
      atomicAdd(&sh2[c0 + i], p2[i]);
    }
    __syncthreads();
    double* st = stats + (blockIdx.x & (SREP - 1)) * 256;
    if (tid < DOUT) {
      atomicAdd(&st[tid], (double)sh1[tid]);
      atomicAdd(&st[DOUT + tid], (double)sh2[tid]);
    }
  }
}

// ---------------- standalone BN stats / coef ----------------
template <int D>
__global__ void bn_stats_kernel(const h16* __restrict__ x, double* __restrict__ stats, int n) {
  int tid = threadIdx.x;
  int c = tid & (D - 1);
  const int rpb = 256 / D;
  float s1 = 0.f, s2 = 0.f;
  for (int r = blockIdx.x * rpb + tid / D; r < n; r += gridDim.x * rpb) {
    float v = (float)x[(size_t)r * D + c];
    s1 += v;
    s2 = fmaf(v, v, s2);
  }
  double* st = stats + (blockIdx.x & (SREP - 1)) * 256;
  atomicAdd(&st[c], (double)s1);
  atomicAdd(&st[D + c], (double)s2);
}

template <int D>
__global__ void bn_coef_kernel(const double* __restrict__ stats, const float* __restrict__ g,
                               const float* __restrict__ b, float* __restrict__ coef, int n) {
  int c = threadIdx.x;
  if (c >= D) return;
  double s1 = 0.0, s2 = 0.0;
#pragma unroll
  for (int r = 0; r < SREP; ++r) {
    s1 += stats[r * 256 + c];
    s2 += stats[r * 256 + D + c];
  }
  double inv_n = 1.0 / (double)n;
  double mu = s1 * inv_n;
  double var = s2 * inv_n - mu * mu;
  float A = (float)(1.0 / sqrt(var + 1e-5)) * g[c];
  coef[c] = A;
  coef[D + c] = b[c] - (float)mu * A;
}

// ---------------- GCN aggregation ----------------
__global__ void gcn_agg16_kernel(const float* __restrict__ h, const int* __restrict__ rowptr,
                                 const int* __restrict__ csr, const float* __restrict__ dis,
                                 h16* __restrict__ out, int n) {
  int wave = (blockIdx.x * blockDim.x + threadIdx.x) >> 6;
  int lane = threadIdx.x & 63;
  if (wave >= n) return;
  int s = rowptr[wave], e = rowptr[wave + 1];
  int q = lane >> 4, c = lane & 15;
  float acc = 0.f;
  for (int k = s + q; k < e; k += 4) {
    int j = csr[k];
    acc = fmaf(dis[j], h[(size_t)j * 16 + c], acc);
  }
  acc += __shfl_xor(acc, 16, 64);
  acc += __shfl_xor(acc, 32, 64);
  if (lane < 16) out[(size_t)wave * 16 + lane] = (h16)(dis[wave] * acc);
}

__global__ void gcn_agg64_kernel(const h16* __restrict__ h, const int* __restrict__ rowptr,
                                 const int* __restrict__ csr, const float* __restrict__ dis,
                                 const float* __restrict__ bias, h16* __restrict__ out, int n) {
  int wave = (blockIdx.x * blockDim.x + threadIdx.x) >> 6;
  int lane = threadIdx.x & 63;
  if (wave >= n) return;
  int s = rfl(rowptr[wave]);
  int e = rfl(rowptr[wave + 1]);
  float a[4] = {0.f, 0.f, 0.f, 0.f};
  int k = s;
  for (; k + 8 <= e; k += 8) {
    int j[8];
    float d[8];
#pragma unroll
    for (int u = 0; u < 8; ++u) j[u] = rfl(csr[k + u]);
#pragma unroll
    for (int u = 0; u < 8; ++u) d[u] = dis[j[u]];
#pragma unroll
    for (int u = 0; u < 8; ++u) {
      const h16* rp = h + (size_t)j[u] * 64;
      a[u & 3] = fmaf(d[u], (float)rp[lane], a[u & 3]);
    }
  }
  for (; k + 4 <= e; k += 4) {
    int j[4];
#pragma unroll
    for (int u = 0; u < 4; ++u) j[u] = rfl(csr[k + u]);
#pragma unroll
    for (int u = 0; u < 4; ++u) {
      const h16* rp = h + (size_t)j[u] * 64;
      a[u] = fmaf(dis[j[u]], (float)rp[lane], a[u]);
    }
  }
  for (; k < e; ++k) {
    int j0 = rfl(csr[k]);
    const h16* rp = h + (size_t)j0 * 64;
    a[0] = fmaf(dis[j0], (float)rp[lane], a[0]);
  }
  float b0 = bias ? bias[lane] : 0.f;
  out[(size_t)wave * 64 + lane] = (h16)fmaf(dis[wave], (a[0] + a[1]) + (a[2] + a[3]), b0);
}

template <bool COEF>
__global__ void gcn_agg128_kernel(const h16* __restrict__ h, const int* __restrict__ rowptr,
                                  const int* __restrict__ csr, const float* __restrict__ dis,
                                  const float* __restrict__ coef, h16* __restrict__ out, int n) {
  int wave = (blockIdx.x * blockDim.x + threadIdx.x) >> 6;
  int lane = threadIdx.x & 63;
  if (wave >= n) return;
  int s = rfl(rowptr[wave]);
  int e = rfl(rowptr[wave + 1]);
  int c2 = lane * 2;
  float2 A2 = make_float2(0.f, 0.f), B2 = make_float2(0.f, 0.f);
  if (COEF) {
    A2 = *(const float2*)(coef + c2);
    B2 = *(const float2*)(coef + 128 + c2);
  }
  float a0[4] = {0.f, 0.f, 0.f, 0.f};
  float a1[4] = {0.f, 0.f, 0.f, 0.f};
  int k = s;
  for (; k + 8 <= e; k += 8) {
    int j[8];
    float d[8];
#pragma unroll
    for (int u = 0; u < 8; ++u) j[u] = rfl(csr[k + u]);
#pragma unroll
    for (int u = 0; u < 8; ++u) d[u] = dis[j[u]];
#pragma unroll
    for (int u = 0; u < 8; ++u) {
      const h16* rp = h + (size_t)j[u] * 128;
      h16x2 v = *(const h16x2*)(rp + c2);
      float f0 = (float)v[0], f1 = (float)v[1];
      if (COEF) {
        f0 = lrelu(fmaf(f0, A2.x, B2.x));
        f1 = lrelu(fmaf(f1, A2.y, B2.y));
      }
      a0[u & 3] = fmaf(d[u], f0, a0[u & 3]);
      a1[u & 3] = fmaf(d[u], f1, a1[u & 3]);
    }
  }
  for (; k < e; ++k) {
    int j0 = rfl(csr[k]);
    float d0 = dis[j0];
    const h16* rp = h + (size_t)j0 * 128;
    h16x2 v = *(const h16x2*)(rp + c2);
    float f0 = (float)v[0], f1 = (float)v[1];
    if (COEF) {
      f0 = lrelu(fmaf(f0, A2.x, B2.x));
      f1 = lrelu(fmaf(f1, A2.y, B2.y));
    }
    a0[0] = fmaf(d0, f0, a0[0]);
    a1[0] = fmaf(d0, f1, a1[0]);
  }
  float di = dis[wave];
  h16x2 r;
  r[0] = (h16)(di * ((a0[0] + a0[1]) + (a0[2] + a0[3])));
  r[1] = (h16)(di * ((a1[0] + a1[1]) + (a1[2] + a1[3])));
  *(h16x2*)(out + (size_t)wave * 128 + c2) = r;
}

// ---------------- GAT ----------------
template <int C>
__global__ void att_coef_kernel(const h16* __restrict__ h2, const float* __restrict__ a_src,
                                const float* __restrict__ a_dst, float* __restrict__ asrc,
                                float* __restrict__ adst, int n) {
  int gid = blockIdx.x * blockDim.x + threadIdx.x;
  if (gid >= n * 4) return;
  int nd = gid >> 2, h = gid & 3;
  const h16* hr = h2 + (size_t)nd * 4 * C + h * C;
  float s1 = 0.f, s2 = 0.f;
#pragma unroll
  for (int c = 0; c < C; ++c) {
    float v = (float)hr[c];
    s1 = fmaf(v, a_src[h * C + c], s1);
    s2 = fmaf(v, a_dst[h * C + c], s2);
  }
  asrc[gid] = s1;
  adst[gid] = s2;
}

// Dedicated softmax-coef pass (r11 lesson: keep the asrc table L2-resident here).
__global__ void edge_coef_kernel(const int* __restrict__ rowptr, const int* __restrict__ csr,
                                 const float* __restrict__ asrc, const float* __restrict__ adst,
                                 float* __restrict__ exbuf, float* __restrict__ dinv, int n) {
  int wave = (blockIdx.x * blockDim.x + threadIdx.x) >> 6;
  int lane = threadIdx.x & 63;
  if (wave >= n) return;
  int h = lane & 3, es = lane >> 2;
  float ad = adst[wave * 4 + h];
  int s = rowptr[wave], e = rowptr[wave + 1];
  float den = 0.f;
  for (int k = s + es; k < e; k += 16) {
    int j = csr[k];
    float v = __expf(lrelu(asrc[j * 4 + h] + ad));
    exbuf[(size_t)k * 4 + h] = v;
    den += v;
  }
  den += __shfl_xor(den, 4, 64);
  den += __shfl_xor(den, 8, 64);
  den += __shfl_xor(den, 16, 64);
  den += __shfl_xor(den, 32, 64);
  if (lane < 4) dinv[wave * 4 + h] = 1.0f / den;
}

// D=64,C=16: residual BN-apply fused (rescoef array).
__global__ void gat_agg64_kernel(const h16* __restrict__ h2, const int* __restrict__ rowptr,
                                 const int* __restrict__ csr, const float* __restrict__ exbuf,
                                 const float* __restrict__ dinv, const float* __restrict__ bias,
                                 const h16* __restrict__ xres, const float* __restrict__ rescoef,
                                 h16* __restrict__ out, int n) {
  int wave = (blockIdx.x * blockDim.x + threadIdx.x) >> 6;
  int lane = threadIdx.x & 63;
  if (wave >= n) return;
  int head = lane >> 4;
  int s = rfl(rowptr[wave]);
  int e = rfl(rowptr[wave + 1]);
  float a[4] = {0.f, 0.f, 0.f, 0.f};
  int k = s;
  for (; k + 8 <= e; k += 8) {
    int j[8];
    float ex[8];
#pragma unroll
    for (int u = 0; u < 8; ++u) {
      j[u] = rfl(csr[k + u]);
      ex[u] = exbuf[(size_t)(k + u) * 4 + head];
    }
#pragma unroll
    for (int u = 0; u < 8; ++u) {
      const h16* rp = h2 + (size_t)j[u] * 64;
      a[u & 3] = fmaf(ex[u], (float)rp[lane], a[u & 3]);
    }
  }
  for (; k + 4 <= e; k += 4) {
    int j[4];
    float ex[4];
#pragma unroll
    for (int u = 0; u < 4; ++u) {
      j[u] = rfl(csr[k + u]);
      ex[u] = exbuf[(size_t)(k + u) * 4 + head];
    }
#pragma unroll
    for (int u = 0; u < 4; ++u) {
      const h16* rp = h2 + (size_t)j[u] * 64;
      a[u] = fmaf(ex[u], (float)rp[lane], a[u]);
    }
  }
  for (; k < e; ++k) {
    int j0 = rfl(csr[k]);
    const h16* rp = h2 + (size_t)j0 * 64;
    a[0] = fmaf(exbuf[(size_t)k * 4 + head], (float)rp[lane], a[0]);
  }
  float dv = dinv[wave * 4 + head];
  size_t base = (size_t)wave * 64;
  float xv = fmaf((float)xres[base + lane], rescoef[lane], rescoef[64 + lane]);
  float v0 = ((a[0] + a[1]) + (a[2] + a[3])) * dv + bias[lane] + xv;
  out[base + lane] = (h16)lrelu(v0);
}

// D=128,C=32: residual BN-apply fused (rescoef array).
__global__ void gat_agg128_kernel(const h16* __restrict__ h2, const int* __restrict__ rowptr,
                                  const int* __restrict__ csr, const float* __restrict__ exbuf,
                                  const float* __restrict__ dinv, const float* __restrict__ bias,
                                  const h16* __restrict__ xres, const float* __restrict__ rescoef,
                                  h16* __restrict__ out, int n) {
  int wave = (blockIdx.x * blockDim.x + threadIdx.x) >> 6;
  int lane = threadIdx.x & 63;
  if (wave >= n) return;
  int head = lane >> 4;
  int c2 = lane * 2;
  int s = rfl(rowptr[wave]);
  int e = rfl(rowptr[wave + 1]);
  float a0[4] = {0.f, 0.f, 0.f, 0.f};
  float a1[4] = {0.f, 0.f, 0.f, 0.f};
  int k = s;
  for (; k + 8 <= e; k += 8) {
    int j[8];
    float ex[8];
#pragma unroll
    for (int u = 0; u < 8; ++u) {
      j[u] = rfl(csr[k + u]);
      ex[u] = exbuf[(size_t)(k + u) * 4 + head];
    }
#pragma unroll
    for (int u = 0; u < 8; ++u) {
      const h16* rp = h2 + (size_t)j[u] * 128;
      h16x2 v = *(const h16x2*)(rp + c2);
      a0[u & 3] = fmaf(ex[u], (float)v[0], a0[u & 3]);
      a1[u & 3] = fmaf(ex[u], (float)v[1], a1[u & 3]);
    }
  }
  for (; k + 4 <= e; k += 4) {
    int j[4];
    float ex[4];
#pragma unroll
    for (int u = 0; u < 4; ++u) {
      j[u] = rfl(csr[k + u]);
      ex[u] = exbuf[(size_t)(k + u) * 4 + head];
    }
#pragma unroll
    for (int u = 0; u < 4; ++u) {
      const h16* rp = h2 + (size_t)j[u] * 128;
      h16x2 v = *(const h16x2*)(rp + c2);
      a0[u] = fmaf(ex[u], (float)v[0], a0[u]);
      a1[u] = fmaf(ex[u], (float)v[1], a1[u]);
    }
  }
  for (; k < e; ++k) {
    int j0 = rfl(csr[k]);
    float e0 = exbuf[(size_t)k * 4 + head];
    const h16* rp = h2 + (size_t)j0 * 128;
    h16x2 v = *(const h16x2*)(rp + c2);
    a0[0] = fmaf(e0, (float)v[0], a0[0]);
    a1[0] = fmaf(e0, (float)v[1], a1[0]);
  }
  float dv = dinv[wave * 4 + head];
  float2 b2 = *(const float2*)(bias + c2);
  float2 A2 = *(const float2*)(rescoef + c2);
  float2 B2 = *(const float2*)(rescoef + 128 + c2);
  size_t base = (size_t)wave * 128;
  h16x2 xr = *(const h16x2*)(xres + base + c2);
  float xr0 = fmaf((float)xr[0], A2.x, B2.x);
  float xr1 = fmaf((float)xr[1], A2.y, B2.y);
  float v0 = ((a0[0] + a0[1]) + (a0[2] + a0[3])) * dv + b2.x + xr0;
  float v1 = ((a1[0] + a1[1]) + (a1[2] + a1[3])) * dv + b2.y + xr1;
  h16x2 r;
  r[0] = (h16)lrelu(v0);
  r[1] = (h16)lrelu(v1);
  *(h16x2*)(out + base + c2) = r;
}

// ---------------- global mean pool (inline bounds + coef array) ----------------
__global__ void pool_kernel(const h16* __restrict__ x, const int* __restrict__ batch,
                            const float* __restrict__ coef, float* __restrict__ out, int n) {
  __shared__ float sh[4][64];
  __shared__ int sb[2];
  int tid = threadIdx.x;
  int gid = blockIdx.x;
  if (tid < 2) {  // lower_bound(batch, gid + tid)
    int key = gid + tid;
    int lo = 0, hi = n;
    while (lo < hi) {
      int mid = (lo + hi) >> 1;
      if (batch[mid] < key)
        lo = mid + 1;
      else
        hi = mid;
    }
    sb[tid] = lo;
  }
  __syncthreads();
  int s = sb[0], e = sb[1];
  int lane = tid & 63, w = tid >> 6;
  float acc = 0.f;
  for (int r = s + w; r < e; r += 4) acc += (float)x[(size_t)r * 64 + lane];
  sh[w][lane] = acc;
  __syncthreads();
  if (w == 0) {
    float t = sh[0][lane] + sh[1][lane] + sh[2][lane] + sh[3][lane];
    float cntf = (float)(e - s);
    out[(gid << 6) + lane] = fmaf(coef[lane], t, coef[64 + lane] * cntf) / fmaxf(cntf, 1.0f);
  }
}

// ---------------- host ----------------
extern "C" void kernel_launch(void* const* d_in, const int* in_sizes, int n_in, void* d_out,
                              int out_size, void* d_ws, size_t ws_size, hipStream_t stream) {
  const float* x_in = (const float*)d_in[0];
  const int* ei = (const int*)d_in[1];
  const int* batch = (const int*)d_in[2];
  const float* gcn_w[4] = {(const float*)d_in[3], (const float*)d_in[7], (const float*)d_in[11],
                           (const float*)d_in[15]};
  const float* gcn_b[4] = {(const float*)d_in[4], (const float*)d_in[8], (const float*)d_in[12],
                           (const float*)d_in[16]};
  const float* bn_g[4] = {(const float*)d_in[5], (const float*)d_in[9], (const float*)d_in[13],
                          (const float*)d_in[17]};
  const float* bn_b[4] = {(const float*)d_in[6], (const float*)d_in[10], (const float*)d_in[14],
                          (const float*)d_in[18]};
  const float* gat_w0 = (const float*)d_in[19];
  const float* gat_as0 = (const float*)d_in[20];
  const float* gat_ad0 = (const float*)d_in[21];
  const float* gat_b0 = (const float*)d_in[22];
  const float* gat_w2 = (const float*)d_in[23];
  const float* gat_as2 = (const float*)d_in[24];
  const float* gat_ad2 = (const float*)d_in[25];
  const float* gat_b2 = (const float*)d_in[26];

  const int N = in_sizes[2];      // 100000
  const int E = in_sizes[1] / 2;  // 1600000

  char* wp = (char*)d_ws;
  auto alloc = [&](size_t bytes) -> void* {
    void* p = (void*)wp;
    wp += (bytes + 255) & ~(size_t)255;
    return p;
  };
  double* statsAll = (double*)alloc(4 * SREP * 256 * sizeof(double));
  float* coefAll = (float*)alloc(4 * 256 * sizeof(float));
  int* rowptr = (int*)alloc((size_t)(N + 1) * 4);
  int* cursor = (int*)alloc((size_t)N * 4);
  int* partial = (int*)alloc(256 * sizeof(int));
  int* csr = (int*)alloc((size_t)(N + E) * 4);
  float* dis = (float*)alloc((size_t)N * 4);
  h16* bufA = (h16*)alloc((size_t)N * 128 * 2);
  h16* bufB = (h16*)alloc((size_t)N * 128 * 2);
  h16* bufC = (h16*)alloc((size_t)N * 128 * 2);
  float* attS = (float*)alloc((size_t)N * 4 * 4);
  float* attD = (float*)alloc((size_t)N * 4 * 4);
  float* exbuf = (float*)alloc((size_t)(N + E) * 4 * 4);
  float* dinv = (float*)alloc((size_t)N * 4 * 4);
  h16* wt0 = (h16*)alloc(64 * 64 * 2);
  h16* wt1 = (h16*)alloc(64 * 128 * 2);
  h16* wt2 = (h16*)alloc(128 * 128 * 2);
  h16* wt3 = (h16*)alloc(128 * 128 * 2);
  h16* wt4 = (h16*)alloc(128 * 64 * 2);
  if ((size_t)(wp - (char*)d_ws) > ws_size) return;

  double* stats0 = statsAll;
  double* stats1 = statsAll + SREP * 256;
  double* stats2 = statsAll + 2 * SREP * 256;
  double* stats3 = statsAll + 3 * SREP * 256;
  float* coef0 = coefAll;
  float* coef1 = coefAll + 256;
  float* coef2 = coefAll + 512;
  float* coef3 = coefAll + 768;

  const int B = 256;
  auto cd = [](int a, int b) { return (a + b - 1) / b; };
  const int scan_blocks = cd(N, SCAN_CHUNK);
  const int nbkt = cd(N, XCDS);

  // --- zero + transposes + CSR build (direct, XCD-bucketed count & fill) ---
  zero_f32_kernel<<<cd(4 * SREP * 512, B), B, 0, stream>>>((float*)statsAll, 4 * SREP * 512);
  wt_all_kernel<<<cd(53248, B), B, 0, stream>>>(gat_w0, gcn_w[1], gcn_w[2], gat_w2, gcn_w[3], wt0,
                                                wt1, wt2, wt3, wt4);
  init_counts_kernel<<<cd(N, B), B, 0, stream>>>(cursor, N);
  count_edges_kernel<<<XCDS * 512, B, 0, stream>>>(ei, cursor, E, nbkt);
  block_sum_kernel<<<scan_blocks, B, 0, stream>>>(cursor, partial, N);
  partial_scan_kernel<<<1, B, 0, stream>>>(partial, rowptr, scan_blocks, N);
  chunk_scan_kernel<<<scan_blocks, B, 0, stream>>>(cursor, partial, rowptr, N);
  finalize_csr_kernel<<<cd(N, B), B, 0, stream>>>(rowptr, dis, cursor, csr, N);
  fill_edges_kernel<<<XCDS * 512, B, 0, stream>>>(ei, cursor, csr, E, nbkt);

  // ---- Layer 0: GCN 16->64 (agg at 16 -> VALU gemm w/ fused stats), BN-coef ----
  gcn_agg16_kernel<<<cd(N * 64, B), B, 0, stream>>>(x_in, rowptr, csr, dis, bufB, N);
  gemm_tile_kernel<16, 64, 8, true>
      <<<cd(N, 128), B, 0, stream>>>(bufB, gcn_w[0], gcn_b[0], bufC, stats0, N);
  bn_coef_kernel<64><<<1, 64, 0, stream>>>(stats0, bn_g[0], bn_b[0], coef0, N);
  // GAT0: MFMA gemm (coef0 on input) -> att_coef -> edge_coef -> gat (coef0 on residual)
  gemm_mfma_kernel<64, 64, false>
      <<<cd(N, 128), B, 0, stream>>>(bufC, wt0, nullptr, coef0, bufB, nullptr, N);
  att_coef_kernel<16><<<cd(N * 4, B), B, 0, stream>>>(bufB, gat_as0, gat_ad0, attS, attD, N);
  edge_coef_kernel<<<cd(N * 64, B), B, 0, stream>>>(rowptr, csr, attS, attD, exbuf, dinv, N);
  gat_agg64_kernel<<<cd(N * 64, B), B, 0, stream>>>(bufB, rowptr, csr, exbuf, dinv, gat_b0, bufC,
                                                    coef0, bufA, N);

  // ---- Layer 1: GCN 64->128 (agg at 64 -> MFMA gemm w/ fused stats), BN-coef ----
  gcn_agg64_kernel<<<cd(N * 64, B), B, 0, stream>>>(bufA, rowptr, csr, dis, nullptr, bufB, N);
  gemm_mfma_kernel<64, 128, true>
      <<<cd(N, 128), B, 0, stream>>>(bufB, wt1, gcn_b[1], nullptr, bufC, stats1, N);
  bn_coef_kernel<128><<<1, 128, 0, stream>>>(stats1, bn_g[1], bn_b[1], coef1, N);

  // ---- Layer 2: GCN 128->128 (agg applies coef1+lrelu) -> MFMA gemm w/ stats, BN-coef ----
  gcn_agg128_kernel<true><<<cd(N * 64, B), B, 0, stream>>>(bufC, rowptr, csr, dis, coef1, bufB, N);
  gemm_mfma_kernel<128, 128, true>
      <<<cd(N, 128), B, 0, stream>>>(bufB, wt2, gcn_b[2], nullptr, bufA, stats2, N);
  bn_coef_kernel<128><<<1, 128, 0, stream>>>(stats2, bn_g[2], bn_b[2], coef2, N);
  // GAT2: MFMA gemm (coef2 on input) -> att_coef -> edge_coef -> gat (coef2 on residual)
  gemm_mfma_kernel<128, 128, false>
      <<<cd(N, 128), B, 0, stream>>>(bufA, wt3, nullptr, coef2, bufB, nullptr, N);
  att_coef_kernel<32><<<cd(N * 4, B), B, 0, stream>>>(bufB, gat_as2, gat_ad2, attS, attD, N);
  edge_coef_kernel<<<cd(N * 64, B), B, 0, stream>>>(rowptr, csr, attS, attD, exbuf, dinv, N);
  gat_agg128_kernel<<<cd(N * 64, B), B, 0, stream>>>(bufB, rowptr, csr, exbuf, dinv, gat_b2, bufA,
                                                     coef2, bufC, N);

  // ---- Layer 3: GCN 128->64 (MFMA gemm -> agg64 w/ bias), stats, BN-coef ----
  gemm_mfma_kernel<128, 64, false>
      <<<cd(N, 128), B, 0, stream>>>(bufC, wt4, nullptr, nullptr, bufB, nullptr, N);
  gcn_agg64_kernel<<<cd(N * 64, B), B, 0, stream>>>(bufB, rowptr, csr, dis, gcn_b[3], bufA, N);
  bn_stats_kernel<64><<<256, 256, 0, stream>>>(bufA, stats3, N);
  bn_coef_kernel<64><<<1, 64, 0, stream>>>(stats3, bn_g[3], bn_b[3], coef3, N);

  // ---- global mean pool (inline bounds + coef3) ----
  pool_kernel<<<GRAPHS, 256, 0, stream>>>(bufA, batch, coef3, (float*)d_out, N);
}